// Round 1
// baseline (4399.130 us; speedup 1.0000x reference)
//
#include <hip/hip_runtime.h>
#include <math.h>

#define EPS 1e-5f

// ---------------- scatter layer 1: msg1[dst] += x[src], cnt[dst]++ ----------
__global__ __launch_bounds__(256) void k_scatter1(
    const int* __restrict__ ei, const float* __restrict__ x,
    float* __restrict__ msg, float* __restrict__ cnt, int E, int n) {
  int t = blockIdx.x * 256 + threadIdx.x;
  int e = t >> 5;
  if (e >= E) return;
  int q = t & 31;                       // float4 index within 128-ch row
  int s = ei[e];
  int d = ei[E + e];
  if ((unsigned)s >= (unsigned)n || (unsigned)d >= (unsigned)n) return;
  float4 v = ((const float4*)x)[(size_t)s * 32 + q];
  float* mp = msg + (size_t)d * 128 + q * 4;
  unsafeAtomicAdd(mp + 0, v.x);
  unsafeAtomicAdd(mp + 1, v.y);
  unsafeAtomicAdd(mp + 2, v.z);
  unsafeAtomicAdd(mp + 3, v.w);
  if (q == 0) unsafeAtomicAdd(cnt + d, 1.0f);
}

// ------------- layer 1 fused: h1 = relu(bn1(agg@W1l + b1 + x@W1r)) ----------
// writes h1 in-place over msg (block stages its rows to LDS first)
__global__ __launch_bounds__(256) void k_lin1(
    const float* __restrict__ x, float* __restrict__ msg,
    const float* __restrict__ cnt,
    const float* __restrict__ Wl, const float* __restrict__ b,
    const float* __restrict__ Wr, const float* __restrict__ g,
    const float* __restrict__ be, int n) {
  __shared__ float aS[16][128];
  __shared__ float xS[16][128];
  __shared__ float invS[16];
  int tid = threadIdx.x;
  int row0 = blockIdx.x * 16;
  if (tid < 16) {
    int r = row0 + tid;
    invS[tid] = 1.0f / fmaxf((r < n) ? cnt[r] : 1.0f, 1.0f);
  }
  __syncthreads();
  for (int it = tid; it < 16 * 128; it += 256) {
    int r = it >> 7, k = it & 127;
    int gr = row0 + r;
    float xv = 0.f, mv = 0.f;
    if (gr < n) {
      size_t o = (size_t)gr * 128 + k;
      xv = x[o];
      mv = msg[o] * invS[r];
    }
    xS[r][k] = xv;
    aS[r][k] = mv;
  }
  __syncthreads();
  int c = tid & 127;
  int ty = tid >> 7;  // 0..1 -> rows ty*8 .. ty*8+7
  float accA[8] = {0.f, 0.f, 0.f, 0.f, 0.f, 0.f, 0.f, 0.f};
  float accB[8] = {0.f, 0.f, 0.f, 0.f, 0.f, 0.f, 0.f, 0.f};
  for (int k = 0; k < 128; k += 4) {
    float wl0 = Wl[(k + 0) * 128 + c], wl1 = Wl[(k + 1) * 128 + c];
    float wl2 = Wl[(k + 2) * 128 + c], wl3 = Wl[(k + 3) * 128 + c];
    float wr0 = Wr[(k + 0) * 128 + c], wr1 = Wr[(k + 1) * 128 + c];
    float wr2 = Wr[(k + 2) * 128 + c], wr3 = Wr[(k + 3) * 128 + c];
#pragma unroll
    for (int i = 0; i < 8; ++i) {
      int r = ty * 8 + i;
      float4 av = *(const float4*)&aS[r][k];
      float4 xv = *(const float4*)&xS[r][k];
      accA[i] += av.x * wl0 + av.y * wl1 + av.z * wl2 + av.w * wl3;
      accB[i] += xv.x * wr0 + xv.y * wr1 + xv.z * wr2 + xv.w * wr3;
    }
  }
  float sc = g[c] * (1.0f / sqrtf(1.0f + EPS));
  float bb = b[c], bt = be[c];
#pragma unroll
  for (int i = 0; i < 8; ++i) {
    int r = row0 + ty * 8 + i;
    if (r < n) {
      float v = (accA[i] + bb + accB[i]) * sc + bt;
      msg[(size_t)r * 128 + c] = fmaxf(v, 0.f);
    }
  }
}

// ------- layer 2 matmuls: y = h1@W2l ; pre(d_out) = b2 + h1@W2r -------------
__global__ __launch_bounds__(256) void k_lin2(
    const float* __restrict__ h,
    const float* __restrict__ Wl, const float* __restrict__ b,
    const float* __restrict__ Wr,
    float* __restrict__ y, float* __restrict__ pre, int n) {
  __shared__ float hS[32][128];
  int tid = threadIdx.x;
  int row0 = blockIdx.x * 32;
  for (int it = tid; it < 32 * 128; it += 256) {
    int r = it >> 7, k = it & 127;
    int gr = row0 + r;
    hS[r][k] = (gr < n) ? h[(size_t)gr * 128 + k] : 0.f;
  }
  __syncthreads();
  int c = tid & 63;
  int ty = tid >> 6;  // 0..3 -> rows ty*8 .. ty*8+7
  float accA[8] = {0.f, 0.f, 0.f, 0.f, 0.f, 0.f, 0.f, 0.f};
  float accB[8] = {0.f, 0.f, 0.f, 0.f, 0.f, 0.f, 0.f, 0.f};
  for (int k = 0; k < 128; k += 4) {
    float wl0 = Wl[(k + 0) * 64 + c], wl1 = Wl[(k + 1) * 64 + c];
    float wl2 = Wl[(k + 2) * 64 + c], wl3 = Wl[(k + 3) * 64 + c];
    float wr0 = Wr[(k + 0) * 64 + c], wr1 = Wr[(k + 1) * 64 + c];
    float wr2 = Wr[(k + 2) * 64 + c], wr3 = Wr[(k + 3) * 64 + c];
#pragma unroll
    for (int i = 0; i < 8; ++i) {
      float4 hv = *(const float4*)&hS[ty * 8 + i][k];
      accA[i] += hv.x * wl0 + hv.y * wl1 + hv.z * wl2 + hv.w * wl3;
      accB[i] += hv.x * wr0 + hv.y * wr1 + hv.z * wr2 + hv.w * wr3;
    }
  }
  float bb = b[c];
#pragma unroll
  for (int i = 0; i < 8; ++i) {
    int r = row0 + ty * 8 + i;
    if (r < n) {
      y[(size_t)r * 64 + c] = accA[i];
      pre[(size_t)r * 64 + c] = accB[i] + bb;
    }
  }
}

// ---------------- scatter layer 2: msg2[dst] += y[src] ----------------------
__global__ __launch_bounds__(256) void k_scatter2(
    const int* __restrict__ ei, const float* __restrict__ y,
    float* __restrict__ msg2, int E, int n) {
  int t = blockIdx.x * 256 + threadIdx.x;
  int e = t >> 4;
  if (e >= E) return;
  int q = t & 15;                       // float4 index within 64-ch row
  int s = ei[e];
  int d = ei[E + e];
  if ((unsigned)s >= (unsigned)n || (unsigned)d >= (unsigned)n) return;
  float4 v = ((const float4*)y)[(size_t)s * 16 + q];
  float* mp = msg2 + (size_t)d * 64 + q * 4;
  unsafeAtomicAdd(mp + 0, v.x);
  unsafeAtomicAdd(mp + 1, v.y);
  unsafeAtomicAdd(mp + 2, v.z);
  unsafeAtomicAdd(mp + 3, v.w);
}

// -------- final: out = relu(bn2(msg2/cnt + pre)) ----------------------------
__global__ __launch_bounds__(256) void k_final(
    const float* __restrict__ msg2, const float* __restrict__ cnt,
    const float* __restrict__ g, const float* __restrict__ be,
    float* __restrict__ out, int n) {
  int i = blockIdx.x * 256 + threadIdx.x;
  if (i >= n * 64) return;
  int r = i >> 6, c = i & 63;
  float inv = 1.0f / fmaxf(cnt[r], 1.0f);
  float sc = g[c] * (1.0f / sqrtf(1.0f + EPS));
  float v = (msg2[i] * inv + out[i]) * sc + be[c];
  out[i] = fmaxf(v, 0.f);
}

extern "C" void kernel_launch(void* const* d_in, const int* in_sizes, int n_in,
                              void* d_out, int out_size, void* d_ws, size_t ws_size,
                              hipStream_t stream) {
  const float* x   = (const float*)d_in[0];
  const int*   ei  = (const int*)d_in[1];
  const float* W1l = (const float*)d_in[2];
  const float* b1  = (const float*)d_in[3];
  const float* W1r = (const float*)d_in[4];
  const float* g1  = (const float*)d_in[5];
  const float* be1 = (const float*)d_in[6];
  const float* W2l = (const float*)d_in[7];
  const float* b2  = (const float*)d_in[8];
  const float* W2r = (const float*)d_in[9];
  const float* g2  = (const float*)d_in[10];
  const float* be2 = (const float*)d_in[11];
  float* out = (float*)d_out;

  int n = in_sizes[0] / 128;
  int E = in_sizes[1] / 2;

  char* ws = (char*)d_ws;
  float* cnt  = (float*)(ws);                       // n floats
  float* msg1 = (float*)(ws + (size_t)524288);      // n*128 floats, becomes h1
  float* y    = (float*)(ws + (size_t)52428800);    // n*64 floats
  float* msg2 = (float*)(ws + (size_t)78643200);    // n*64 floats

  hipMemsetAsync(cnt,  0, (size_t)n * 4, stream);
  hipMemsetAsync(msg1, 0, (size_t)n * 128 * 4, stream);
  hipMemsetAsync(msg2, 0, (size_t)n * 64 * 4, stream);

  {
    long long T = (long long)E * 32;
    k_scatter1<<<(int)((T + 255) / 256), 256, 0, stream>>>(ei, x, msg1, cnt, E, n);
  }
  k_lin1<<<(n + 15) / 16, 256, 0, stream>>>(x, msg1, cnt, W1l, b1, W1r, g1, be1, n);
  k_lin2<<<(n + 31) / 32, 256, 0, stream>>>(msg1, W2l, b2, W2r, y, out, n);
  {
    long long T = (long long)E * 16;
    k_scatter2<<<(int)((T + 255) / 256), 256, 0, stream>>>(ei, y, msg2, E, n);
  }
  k_final<<<(n * 64 + 255) / 256, 256, 0, stream>>>(msg2, cnt, g2, be2, out, n);
}

// Round 2
// 768.856 us; speedup vs baseline: 5.7217x; 5.7217x over previous
//
#include <hip/hip_runtime.h>
#include <math.h>

#define EPS 1e-5f

// ---------------- degree histogram ------------------------------------------
__global__ __launch_bounds__(256) void k_deg(
    const int* __restrict__ ei, int* __restrict__ deg, int E, int n) {
  int e = blockIdx.x * 256 + threadIdx.x;
  if (e >= E) return;
  int d = ei[E + e];
  if ((unsigned)d < (unsigned)n) atomicAdd(&deg[d], 1);
}

// ---------------- 3-step exclusive scan -> rowptr ---------------------------
__global__ __launch_bounds__(256) void k_scan1(
    const int* __restrict__ deg, int* __restrict__ incl,
    int* __restrict__ bsum, int n) {
  __shared__ int s[256];
  int t = threadIdx.x;
  int base = blockIdx.x * 1024 + t * 4;
  int v0 = (base + 0 < n) ? deg[base + 0] : 0;
  int v1 = (base + 1 < n) ? deg[base + 1] : 0;
  int v2 = (base + 2 < n) ? deg[base + 2] : 0;
  int v3 = (base + 3 < n) ? deg[base + 3] : 0;
  int sum = v0 + v1 + v2 + v3;
  s[t] = sum;
  __syncthreads();
  for (int off = 1; off < 256; off <<= 1) {
    int xv = (t >= off) ? s[t - off] : 0;
    __syncthreads();
    s[t] += xv;
    __syncthreads();
  }
  int excl = s[t] - sum;
  int a0 = excl + v0, a1 = a0 + v1, a2 = a1 + v2, a3 = a2 + v3;
  if (base + 0 < n) incl[base + 0] = a0;
  if (base + 1 < n) incl[base + 1] = a1;
  if (base + 2 < n) incl[base + 2] = a2;
  if (base + 3 < n) incl[base + 3] = a3;
  if (t == 255) bsum[blockIdx.x] = s[255];
}

__global__ void k_scan2(int* bsum, int nb) {
  if (threadIdx.x == 0 && blockIdx.x == 0) {
    int acc = 0;
    for (int i = 0; i < nb; ++i) { int v = bsum[i]; bsum[i] = acc; acc += v; }
  }
}

__global__ __launch_bounds__(256) void k_scan3(
    const int* __restrict__ incl, const int* __restrict__ bsum,
    int* __restrict__ rowptr, int n) {
  int i = blockIdx.x * 256 + threadIdx.x;
  if (i < n) rowptr[i + 1] = incl[i] + bsum[i >> 10];
  if (i == 0) rowptr[0] = 0;
}

// ---------------- edge placement into CSR order -----------------------------
__global__ __launch_bounds__(256) void k_place(
    const int* __restrict__ ei, int* __restrict__ cursor,
    int* __restrict__ ssrc, int E, int n) {
  int e = blockIdx.x * 256 + threadIdx.x;
  if (e >= E) return;
  int s = ei[e], d = ei[E + e];
  if ((unsigned)d >= (unsigned)n) return;
  int pos = atomicAdd(&cursor[d], 1);
  ssrc[pos] = s;
}

// ---------------- gather-mean layer 1: agg[n] = mean(x[neighbors]) ----------
__global__ __launch_bounds__(256) void k_agg1(
    const int* __restrict__ rowptr, const int* __restrict__ ssrc,
    const float* __restrict__ x, float* __restrict__ agg, int n) {
  int w = (blockIdx.x * 256 + threadIdx.x) >> 6;  // wave -> node
  int l = threadIdx.x & 63;                       // lane -> 2 channels
  if (w >= n) return;
  int beg = rowptr[w], end = rowptr[w + 1];
  float ax = 0.f, ay = 0.f;
  for (int p = beg; p < end; ++p) {
    int s = ssrc[p];
    float2 v = ((const float2*)x)[(size_t)s * 64 + l];
    ax += v.x; ay += v.y;
  }
  float inv = 1.0f / fmaxf((float)(end - beg), 1.0f);
  float2 o; o.x = ax * inv; o.y = ay * inv;
  ((float2*)agg)[(size_t)w * 64 + l] = o;
}

// ------------- layer 1 fused: h1 = relu(bn1(agg@W1l + b1 + x@W1r)) ----------
// writes h1 in-place over agg (block stages its rows to LDS first)
__global__ __launch_bounds__(256) void k_lin1(
    const float* __restrict__ x, float* __restrict__ agg,
    const float* __restrict__ Wl, const float* __restrict__ b,
    const float* __restrict__ Wr, const float* __restrict__ g,
    const float* __restrict__ be, int n) {
  __shared__ float aS[16][128];
  __shared__ float xS[16][128];
  int tid = threadIdx.x;
  int row0 = blockIdx.x * 16;
  for (int it = tid; it < 16 * 128; it += 256) {
    int r = it >> 7, k = it & 127;
    int gr = row0 + r;
    float xv = 0.f, mv = 0.f;
    if (gr < n) {
      size_t o = (size_t)gr * 128 + k;
      xv = x[o];
      mv = agg[o];
    }
    xS[r][k] = xv;
    aS[r][k] = mv;
  }
  __syncthreads();
  int c = tid & 127;
  int ty = tid >> 7;  // 0..1 -> rows ty*8 .. ty*8+7
  float accA[8] = {0.f, 0.f, 0.f, 0.f, 0.f, 0.f, 0.f, 0.f};
  float accB[8] = {0.f, 0.f, 0.f, 0.f, 0.f, 0.f, 0.f, 0.f};
  for (int k = 0; k < 128; k += 4) {
    float wl0 = Wl[(k + 0) * 128 + c], wl1 = Wl[(k + 1) * 128 + c];
    float wl2 = Wl[(k + 2) * 128 + c], wl3 = Wl[(k + 3) * 128 + c];
    float wr0 = Wr[(k + 0) * 128 + c], wr1 = Wr[(k + 1) * 128 + c];
    float wr2 = Wr[(k + 2) * 128 + c], wr3 = Wr[(k + 3) * 128 + c];
#pragma unroll
    for (int i = 0; i < 8; ++i) {
      int r = ty * 8 + i;
      float4 av = *(const float4*)&aS[r][k];
      float4 xv = *(const float4*)&xS[r][k];
      accA[i] += av.x * wl0 + av.y * wl1 + av.z * wl2 + av.w * wl3;
      accB[i] += xv.x * wr0 + xv.y * wr1 + xv.z * wr2 + xv.w * wr3;
    }
  }
  float sc = g[c] * (1.0f / sqrtf(1.0f + EPS));
  float bb = b[c], bt = be[c];
#pragma unroll
  for (int i = 0; i < 8; ++i) {
    int r = row0 + ty * 8 + i;
    if (r < n) {
      float v = (accA[i] + bb + accB[i]) * sc + bt;
      agg[(size_t)r * 128 + c] = fmaxf(v, 0.f);
    }
  }
}

// ------- layer 2 matmuls: y = h1@W2l ; pre(d_out) = b2 + h1@W2r -------------
__global__ __launch_bounds__(256) void k_lin2(
    const float* __restrict__ h,
    const float* __restrict__ Wl, const float* __restrict__ b,
    const float* __restrict__ Wr,
    float* __restrict__ y, float* __restrict__ pre, int n) {
  __shared__ float hS[32][128];
  int tid = threadIdx.x;
  int row0 = blockIdx.x * 32;
  for (int it = tid; it < 32 * 128; it += 256) {
    int r = it >> 7, k = it & 127;
    int gr = row0 + r;
    hS[r][k] = (gr < n) ? h[(size_t)gr * 128 + k] : 0.f;
  }
  __syncthreads();
  int c = tid & 63;
  int ty = tid >> 6;  // 0..3 -> rows ty*8 .. ty*8+7
  float accA[8] = {0.f, 0.f, 0.f, 0.f, 0.f, 0.f, 0.f, 0.f};
  float accB[8] = {0.f, 0.f, 0.f, 0.f, 0.f, 0.f, 0.f, 0.f};
  for (int k = 0; k < 128; k += 4) {
    float wl0 = Wl[(k + 0) * 64 + c], wl1 = Wl[(k + 1) * 64 + c];
    float wl2 = Wl[(k + 2) * 64 + c], wl3 = Wl[(k + 3) * 64 + c];
    float wr0 = Wr[(k + 0) * 64 + c], wr1 = Wr[(k + 1) * 64 + c];
    float wr2 = Wr[(k + 2) * 64 + c], wr3 = Wr[(k + 3) * 64 + c];
#pragma unroll
    for (int i = 0; i < 8; ++i) {
      float4 hv = *(const float4*)&hS[ty * 8 + i][k];
      accA[i] += hv.x * wl0 + hv.y * wl1 + hv.z * wl2 + hv.w * wl3;
      accB[i] += hv.x * wr0 + hv.y * wr1 + hv.z * wr2 + hv.w * wr3;
    }
  }
  float bb = b[c];
#pragma unroll
  for (int i = 0; i < 8; ++i) {
    int r = row0 + ty * 8 + i;
    if (r < n) {
      y[(size_t)r * 64 + c] = accA[i];
      pre[(size_t)r * 64 + c] = accB[i] + bb;
    }
  }
}

// ------ gather-mean layer 2 fused with final BN+ReLU ------------------------
// out = relu(bn2(mean(y[neighbors]) + pre));  pre lives in d_out
__global__ __launch_bounds__(256) void k_agg2(
    const int* __restrict__ rowptr, const int* __restrict__ ssrc,
    const float* __restrict__ y, const float* __restrict__ g,
    const float* __restrict__ be, float* __restrict__ out, int n) {
  int w = (blockIdx.x * 256 + threadIdx.x) >> 6;  // wave -> node
  int l = threadIdx.x & 63;                       // lane -> channel
  if (w >= n) return;
  int beg = rowptr[w], end = rowptr[w + 1];
  float acc = 0.f;
  for (int p = beg; p < end; ++p) {
    int s = ssrc[p];
    acc += y[(size_t)s * 64 + l];
  }
  float inv = 1.0f / fmaxf((float)(end - beg), 1.0f);
  float sc = g[l] * (1.0f / sqrtf(1.0f + EPS));
  size_t o = (size_t)w * 64 + l;
  float v = (acc * inv + out[o]) * sc + be[l];
  out[o] = fmaxf(v, 0.f);
}

extern "C" void kernel_launch(void* const* d_in, const int* in_sizes, int n_in,
                              void* d_out, int out_size, void* d_ws, size_t ws_size,
                              hipStream_t stream) {
  const float* x   = (const float*)d_in[0];
  const int*   ei  = (const int*)d_in[1];
  const float* W1l = (const float*)d_in[2];
  const float* b1  = (const float*)d_in[3];
  const float* W1r = (const float*)d_in[4];
  const float* g1  = (const float*)d_in[5];
  const float* be1 = (const float*)d_in[6];
  const float* W2l = (const float*)d_in[7];
  const float* b2  = (const float*)d_in[8];
  const float* W2r = (const float*)d_in[9];
  const float* g2  = (const float*)d_in[10];
  const float* be2 = (const float*)d_in[11];
  float* out = (float*)d_out;

  int n = in_sizes[0] / 128;
  int E = in_sizes[1] / 2;
  int nb = (n + 1023) / 1024;

  // workspace carve-up (aligned to 256B)
  char* ws = (char*)d_ws;
  size_t o = 0;
  auto carve = [&](size_t bytes) {
    char* p = ws + o;
    o += (bytes + 255) & ~(size_t)255;
    return p;
  };
  int*   deg    = (int*)carve((size_t)n * 4);
  int*   rowptr = (int*)carve((size_t)(n + 1) * 4);
  int*   cursor = (int*)carve((size_t)n * 4);
  int*   incl   = (int*)carve((size_t)n * 4);
  int*   bsum   = (int*)carve((size_t)nb * 4);
  int*   ssrc   = (int*)carve((size_t)E * 4);
  float* agg    = (float*)carve((size_t)n * 128 * 4);  // becomes h1 in place
  float* y      = (float*)carve((size_t)n * 64 * 4);

  hipMemsetAsync(deg, 0, (size_t)n * 4, stream);

  k_deg<<<(E + 255) / 256, 256, 0, stream>>>(ei, deg, E, n);
  k_scan1<<<nb, 256, 0, stream>>>(deg, incl, bsum, n);
  k_scan2<<<1, 64, 0, stream>>>(bsum, nb);
  k_scan3<<<(n + 255) / 256, 256, 0, stream>>>(incl, bsum, rowptr, n);
  hipMemcpyAsync(cursor, rowptr, (size_t)n * 4, hipMemcpyDeviceToDevice, stream);
  k_place<<<(E + 255) / 256, 256, 0, stream>>>(ei, cursor, ssrc, E, n);

  {
    long long T = (long long)n * 64;
    k_agg1<<<(int)((T + 255) / 256), 256, 0, stream>>>(rowptr, ssrc, x, agg, n);
  }
  k_lin1<<<(n + 15) / 16, 256, 0, stream>>>(x, agg, W1l, b1, W1r, g1, be1, n);
  k_lin2<<<(n + 31) / 32, 256, 0, stream>>>(agg, W2l, b2, W2r, y, out, n);
  {
    long long T = (long long)n * 64;
    k_agg2<<<(int)((T + 255) / 256), 256, 0, stream>>>(rowptr, ssrc, y, g2, be2, out, n);
  }
}

// Round 3
// 600.533 us; speedup vs baseline: 7.3254x; 1.2803x over previous
//
#include <hip/hip_runtime.h>
#include <math.h>

#define EPS 1e-5f

typedef __attribute__((ext_vector_type(8))) short short8;
typedef __attribute__((ext_vector_type(4))) float f32x4;

__device__ __forceinline__ short f2bf(float f) {
  union { float f; unsigned u; } v; v.f = f;
  unsigned r = v.u + 0x7fff + ((v.u >> 16) & 1);   // RNE
  return (short)(r >> 16);
}

// ---------------- degree histogram ------------------------------------------
__global__ __launch_bounds__(256) void k_deg(
    const int* __restrict__ ei, int* __restrict__ deg, int E, int n) {
  int e = blockIdx.x * 256 + threadIdx.x;
  if (e >= E) return;
  int d = ei[E + e];
  if ((unsigned)d < (unsigned)n) atomicAdd(&deg[d], 1);
}

// ---------------- 3-step exclusive scan -> rowptr ---------------------------
__global__ __launch_bounds__(256) void k_scan1(
    const int* __restrict__ deg, int* __restrict__ incl,
    int* __restrict__ bsum, int n) {
  __shared__ int s[256];
  int t = threadIdx.x;
  int base = blockIdx.x * 1024 + t * 4;
  int v0 = (base + 0 < n) ? deg[base + 0] : 0;
  int v1 = (base + 1 < n) ? deg[base + 1] : 0;
  int v2 = (base + 2 < n) ? deg[base + 2] : 0;
  int v3 = (base + 3 < n) ? deg[base + 3] : 0;
  int sum = v0 + v1 + v2 + v3;
  s[t] = sum;
  __syncthreads();
  for (int off = 1; off < 256; off <<= 1) {
    int xv = (t >= off) ? s[t - off] : 0;
    __syncthreads();
    s[t] += xv;
    __syncthreads();
  }
  int excl = s[t] - sum;
  int a0 = excl + v0, a1 = a0 + v1, a2 = a1 + v2, a3 = a2 + v3;
  if (base + 0 < n) incl[base + 0] = a0;
  if (base + 1 < n) incl[base + 1] = a1;
  if (base + 2 < n) incl[base + 2] = a2;
  if (base + 3 < n) incl[base + 3] = a3;
  if (t == 255) bsum[blockIdx.x] = s[255];
}

__global__ void k_scan2(int* bsum, int nb) {
  if (threadIdx.x == 0 && blockIdx.x == 0) {
    int acc = 0;
    for (int i = 0; i < nb; ++i) { int v = bsum[i]; bsum[i] = acc; acc += v; }
  }
}

__global__ __launch_bounds__(256) void k_scan3(
    const int* __restrict__ incl, const int* __restrict__ bsum,
    int* __restrict__ rowptr, int n) {
  int i = blockIdx.x * 256 + threadIdx.x;
  if (i < n) rowptr[i + 1] = incl[i] + bsum[i >> 10];
  if (i == 0) rowptr[0] = 0;
}

// ---------------- edge placement into CSR order -----------------------------
__global__ __launch_bounds__(256) void k_place(
    const int* __restrict__ ei, int* __restrict__ cursor,
    int* __restrict__ ssrc, int E, int n) {
  int e = blockIdx.x * 256 + threadIdx.x;
  if (e >= E) return;
  int s = ei[e], d = ei[E + e];
  if ((unsigned)d >= (unsigned)n) return;
  int pos = atomicAdd(&cursor[d], 1);
  ssrc[pos] = s;
}

// ---------------- gather-mean layer 1: agg[n] = mean(x[neighbors]) ----------
__global__ __launch_bounds__(256) void k_agg1(
    const int* __restrict__ rowptr, const int* __restrict__ ssrc,
    const float* __restrict__ x, float* __restrict__ agg, int n) {
  int w = (blockIdx.x * 256 + threadIdx.x) >> 6;  // wave -> node
  int l = threadIdx.x & 63;                       // lane -> 2 channels
  if (w >= n) return;
  int beg = rowptr[w], end = rowptr[w + 1];
  float ax = 0.f, ay = 0.f;
  for (int p = beg; p < end; ++p) {
    int s = ssrc[p];
    float2 v = ((const float2*)x)[(size_t)s * 64 + l];
    ax += v.x; ay += v.y;
  }
  float inv = 1.0f / fmaxf((float)(end - beg), 1.0f);
  float2 o; o.x = ax * inv; o.y = ay * inv;
  ((float2*)agg)[(size_t)w * 64 + l] = o;
}

// ------------- weight packing into MFMA B-fragment order --------------------
// lin1: Wcat[256][128] = [W1l ; W1r], frag f=(kt*8+ct), lane l holds
//       W[kt*32+(l>>4)*8+j][ct*16+(l&15)] for j=0..7
__global__ __launch_bounds__(256) void k_pack1(
    const float* __restrict__ Wl, const float* __restrict__ Wr,
    short* __restrict__ dst) {
  int t = blockIdx.x * 256 + threadIdx.x;  // 64 frags * 64 lanes
  if (t >= 64 * 64) return;
  int l = t & 63, f = t >> 6;
  int kt = f >> 3, ct = f & 7;
  int c = ct * 16 + (l & 15);
  int kb = kt * 32 + (l >> 4) * 8;
  short8 v;
#pragma unroll
  for (int j = 0; j < 8; ++j) {
    int k = kb + j;
    float w = (k < 128) ? Wl[k * 128 + c] : Wr[(k - 128) * 128 + c];
    v[j] = f2bf(w);
  }
  *(short8*)(dst + (size_t)t * 8) = v;
}

// lin2: Wcat[128][128] = [W2l | W2r] (cols 0-63 from W2l, 64-127 from W2r)
__global__ __launch_bounds__(256) void k_pack2(
    const float* __restrict__ Wl, const float* __restrict__ Wr,
    short* __restrict__ dst) {
  int t = blockIdx.x * 256 + threadIdx.x;  // 32 frags * 64 lanes
  if (t >= 32 * 64) return;
  int l = t & 63, f = t >> 6;
  int kt = f >> 3, ct = f & 7;
  int c = ct * 16 + (l & 15);
  int kb = kt * 32 + (l >> 4) * 8;
  short8 v;
#pragma unroll
  for (int j = 0; j < 8; ++j) {
    int k = kb + j;
    float w = (c < 64) ? Wl[k * 64 + c] : Wr[k * 64 + (c - 64)];
    v[j] = f2bf(w);
  }
  *(short8*)(dst + (size_t)t * 8) = v;
}

// ------------- layer 1 MFMA: h1 = relu(bn1([agg|x] @ Wcat1 + b1)) -----------
// writes h1 in-place over agg (block stages its rows to LDS first)
__global__ __launch_bounds__(256) void k_lin1(
    const float* __restrict__ x, float* __restrict__ agg,
    const short* __restrict__ wp, const float* __restrict__ b,
    const float* __restrict__ g, const float* __restrict__ be, int n) {
  __shared__ short As[64 * 256];  // 64 rows x 256 k, bf16, XOR-swizzled, 32 KB
  int tid = threadIdx.x;
  int row0 = blockIdx.x * 64;
#pragma unroll
  for (int it = 0; it < 8; ++it) {
    int slot = it * 256 + tid;     // 0..2047
    int r = slot >> 5;             // row 0..63
    int k8 = slot & 31;            // 8-float chunk 0..31 (k<128: agg, else x)
    int gr = row0 + r;
    float4 v0 = {0, 0, 0, 0}, v1 = {0, 0, 0, 0};
    if (gr < n) {
      const float* src = (k8 < 16) ? (agg + (size_t)gr * 128 + k8 * 8)
                                   : (x + (size_t)gr * 128 + (k8 - 16) * 8);
      v0 = *(const float4*)src;
      v1 = *(const float4*)(src + 4);
    }
    short8 o;
    o[0] = f2bf(v0.x); o[1] = f2bf(v0.y); o[2] = f2bf(v0.z); o[3] = f2bf(v0.w);
    o[4] = f2bf(v1.x); o[5] = f2bf(v1.y); o[6] = f2bf(v1.z); o[7] = f2bf(v1.w);
    int byte = r * 512 + ((k8 * 16) ^ ((r & 7) << 4));
    *(short8*)((char*)As + byte) = o;
  }
  __syncthreads();
  int w = tid >> 6, l = tid & 63;
  int rloc = w * 16 + (l & 15);
  f32x4 acc[8];
#pragma unroll
  for (int i = 0; i < 8; ++i) acc[i] = (f32x4){0.f, 0.f, 0.f, 0.f};
#pragma unroll
  for (int kt = 0; kt < 8; ++kt) {
    int abyte = rloc * 512 + ((kt * 64 + (l >> 4) * 16) ^ ((rloc & 7) << 4));
    short8 a = *(short8*)((char*)As + abyte);
#pragma unroll
    for (int ct = 0; ct < 8; ++ct) {
      short8 bf = *(const short8*)(wp + ((size_t)((kt * 8 + ct) * 64 + l)) * 8);
      acc[ct] = __builtin_amdgcn_mfma_f32_16x16x32_bf16(a, bf, acc[ct], 0, 0, 0);
    }
  }
  // epilogue: C/D layout col=lane&15, row=(lane>>4)*4+q
  int rbase = row0 + w * 16 + (l >> 4) * 4;
  int cb = l & 15;
#pragma unroll
  for (int ct = 0; ct < 8; ++ct) {
    int c = ct * 16 + cb;
    float sc = g[c] * (1.0f / sqrtf(1.0f + EPS));
    float bb = b[c], bt = be[c];
#pragma unroll
    for (int q = 0; q < 4; ++q) {
      int r = rbase + q;
      if (r < n) {
        float v = (acc[ct][q] + bb) * sc + bt;
        agg[(size_t)r * 128 + c] = fmaxf(v, 0.f);
      }
    }
  }
}

// ------- layer 2 MFMA: [y | pre] = h1 @ Wcat2 (+b2 on pre half) -------------
__global__ __launch_bounds__(256) void k_lin2(
    const float* __restrict__ h, const short* __restrict__ wp,
    const float* __restrict__ b2,
    float* __restrict__ y, float* __restrict__ pre, int n) {
  __shared__ short As[64 * 128];  // 16 KB
  int tid = threadIdx.x;
  int row0 = blockIdx.x * 64;
#pragma unroll
  for (int it = 0; it < 4; ++it) {
    int slot = it * 256 + tid;     // 0..1023
    int r = slot >> 4;             // row 0..63
    int k8 = slot & 15;
    int gr = row0 + r;
    float4 v0 = {0, 0, 0, 0}, v1 = {0, 0, 0, 0};
    if (gr < n) {
      const float* src = h + (size_t)gr * 128 + k8 * 8;
      v0 = *(const float4*)src;
      v1 = *(const float4*)(src + 4);
    }
    short8 o;
    o[0] = f2bf(v0.x); o[1] = f2bf(v0.y); o[2] = f2bf(v0.z); o[3] = f2bf(v0.w);
    o[4] = f2bf(v1.x); o[5] = f2bf(v1.y); o[6] = f2bf(v1.z); o[7] = f2bf(v1.w);
    int byte = r * 256 + ((k8 * 16) ^ ((r & 7) << 4));
    *(short8*)((char*)As + byte) = o;
  }
  __syncthreads();
  int w = tid >> 6, l = tid & 63;
  int rloc = w * 16 + (l & 15);
  f32x4 acc[8];
#pragma unroll
  for (int i = 0; i < 8; ++i) acc[i] = (f32x4){0.f, 0.f, 0.f, 0.f};
#pragma unroll
  for (int kt = 0; kt < 4; ++kt) {
    int abyte = rloc * 256 + ((kt * 64 + (l >> 4) * 16) ^ ((rloc & 7) << 4));
    short8 a = *(short8*)((char*)As + abyte);
#pragma unroll
    for (int ct = 0; ct < 8; ++ct) {
      short8 bf = *(const short8*)(wp + ((size_t)((kt * 8 + ct) * 64 + l)) * 8);
      acc[ct] = __builtin_amdgcn_mfma_f32_16x16x32_bf16(a, bf, acc[ct], 0, 0, 0);
    }
  }
  int rbase = row0 + w * 16 + (l >> 4) * 4;
  int cb = l & 15;
#pragma unroll
  for (int ct = 0; ct < 8; ++ct) {
    int c = ct * 16 + cb;
#pragma unroll
    for (int q = 0; q < 4; ++q) {
      int r = rbase + q;
      if (r < n) {
        if (c < 64) y[(size_t)r * 64 + c] = acc[ct][q];
        else        pre[(size_t)r * 64 + (c - 64)] = acc[ct][q] + b2[c - 64];
      }
    }
  }
}

// ------ gather-mean layer 2 fused with final BN+ReLU ------------------------
// out = relu(bn2(mean(y[neighbors]) + pre));  pre lives in d_out
__global__ __launch_bounds__(256) void k_agg2(
    const int* __restrict__ rowptr, const int* __restrict__ ssrc,
    const float* __restrict__ y, const float* __restrict__ g,
    const float* __restrict__ be, float* __restrict__ out, int n) {
  int w = (blockIdx.x * 256 + threadIdx.x) >> 6;  // wave -> node
  int l = threadIdx.x & 63;                       // lane -> channel
  if (w >= n) return;
  int beg = rowptr[w], end = rowptr[w + 1];
  float acc = 0.f;
  for (int p = beg; p < end; ++p) {
    int s = ssrc[p];
    acc += y[(size_t)s * 64 + l];
  }
  float inv = 1.0f / fmaxf((float)(end - beg), 1.0f);
  float sc = g[l] * (1.0f / sqrtf(1.0f + EPS));
  size_t o = (size_t)w * 64 + l;
  float v = (acc * inv + out[o]) * sc + be[l];
  out[o] = fmaxf(v, 0.f);
}

extern "C" void kernel_launch(void* const* d_in, const int* in_sizes, int n_in,
                              void* d_out, int out_size, void* d_ws, size_t ws_size,
                              hipStream_t stream) {
  const float* x   = (const float*)d_in[0];
  const int*   ei  = (const int*)d_in[1];
  const float* W1l = (const float*)d_in[2];
  const float* b1  = (const float*)d_in[3];
  const float* W1r = (const float*)d_in[4];
  const float* g1  = (const float*)d_in[5];
  const float* be1 = (const float*)d_in[6];
  const float* W2l = (const float*)d_in[7];
  const float* b2  = (const float*)d_in[8];
  const float* W2r = (const float*)d_in[9];
  const float* g2  = (const float*)d_in[10];
  const float* be2 = (const float*)d_in[11];
  float* out = (float*)d_out;

  int n = in_sizes[0] / 128;
  int E = in_sizes[1] / 2;
  int nb = (n + 1023) / 1024;

  // workspace carve-up (aligned to 256B)
  char* ws = (char*)d_ws;
  size_t o = 0;
  auto carve = [&](size_t bytes) {
    char* p = ws + o;
    o += (bytes + 255) & ~(size_t)255;
    return p;
  };
  int*   deg    = (int*)carve((size_t)n * 4);
  int*   rowptr = (int*)carve((size_t)(n + 1) * 4);
  int*   cursor = (int*)carve((size_t)n * 4);
  int*   incl   = (int*)carve((size_t)n * 4);
  int*   bsum   = (int*)carve((size_t)nb * 4);
  int*   ssrc   = (int*)carve((size_t)E * 4);
  short* wp1    = (short*)carve((size_t)64 * 64 * 8 * 2);  // 64 KB
  short* wp2    = (short*)carve((size_t)32 * 64 * 8 * 2);  // 32 KB
  float* agg    = (float*)carve((size_t)n * 128 * 4);      // becomes h1 in place
  float* y      = (float*)carve((size_t)n * 64 * 4);

  hipMemsetAsync(deg, 0, (size_t)n * 4, stream);

  k_deg<<<(E + 255) / 256, 256, 0, stream>>>(ei, deg, E, n);
  k_scan1<<<nb, 256, 0, stream>>>(deg, incl, bsum, n);
  k_scan2<<<1, 64, 0, stream>>>(bsum, nb);
  k_scan3<<<(n + 255) / 256, 256, 0, stream>>>(incl, bsum, rowptr, n);
  hipMemcpyAsync(cursor, rowptr, (size_t)n * 4, hipMemcpyDeviceToDevice, stream);
  k_place<<<(E + 255) / 256, 256, 0, stream>>>(ei, cursor, ssrc, E, n);
  k_pack1<<<16, 256, 0, stream>>>(W1l, W1r, wp1);
  k_pack2<<<8, 256, 0, stream>>>(W2l, W2r, wp2);

  {
    long long T = (long long)n * 64;
    k_agg1<<<(int)((T + 255) / 256), 256, 0, stream>>>(rowptr, ssrc, x, agg, n);
  }
  k_lin1<<<(n + 63) / 64, 256, 0, stream>>>(x, agg, wp1, b1, g1, be1, n);
  k_lin2<<<(n + 63) / 64, 256, 0, stream>>>(agg, wp2, b2, y, out, n);
  {
    long long T = (long long)n * 64;
    k_agg2<<<(int)((T + 255) / 256), 256, 0, stream>>>(rowptr, ssrc, y, g2, be2, out, n);
  }
}

// Round 4
// 432.862 us; speedup vs baseline: 10.1629x; 1.3874x over previous
//
#include <hip/hip_runtime.h>
#include <math.h>

#define EPS 1e-5f

typedef __attribute__((ext_vector_type(8))) short short8;
typedef __attribute__((ext_vector_type(4))) float f32x4;

__device__ __forceinline__ short f2bf(float f) {
  union { float f; unsigned u; } v; v.f = f;
  unsigned r = v.u + 0x7fff + ((v.u >> 16) & 1);   // RNE
  return (short)(r >> 16);
}
__device__ __forceinline__ float bf2f(unsigned short u) {
  union { unsigned u; float f; } v; v.u = ((unsigned)u) << 16; return v.f;
}

// ---------------- fp32 -> bf16 cast (x) -------------------------------------
__global__ __launch_bounds__(256) void k_cast(
    const float* __restrict__ in, unsigned short* __restrict__ outb,
    long long n8) {
  long long i = (long long)blockIdx.x * 256 + threadIdx.x;
  if (i >= n8) return;
  const float4* p = (const float4*)in + i * 2;
  float4 v0 = p[0], v1 = p[1];
  short8 o;
  o[0] = f2bf(v0.x); o[1] = f2bf(v0.y); o[2] = f2bf(v0.z); o[3] = f2bf(v0.w);
  o[4] = f2bf(v1.x); o[5] = f2bf(v1.y); o[6] = f2bf(v1.z); o[7] = f2bf(v1.w);
  ((short8*)outb)[i] = o;
}

// ---------------- degree histogram ------------------------------------------
__global__ __launch_bounds__(256) void k_deg(
    const int* __restrict__ ei, int* __restrict__ deg, int E, int n) {
  int e = blockIdx.x * 256 + threadIdx.x;
  if (e >= E) return;
  int d = ei[E + e];
  if ((unsigned)d < (unsigned)n) atomicAdd(&deg[d], 1);
}

// ---------------- 3-step exclusive scan -> rowptr ---------------------------
__global__ __launch_bounds__(256) void k_scan1(
    const int* __restrict__ deg, int* __restrict__ incl,
    int* __restrict__ bsum, int n) {
  __shared__ int s[256];
  int t = threadIdx.x;
  int base = blockIdx.x * 1024 + t * 4;
  int v0 = (base + 0 < n) ? deg[base + 0] : 0;
  int v1 = (base + 1 < n) ? deg[base + 1] : 0;
  int v2 = (base + 2 < n) ? deg[base + 2] : 0;
  int v3 = (base + 3 < n) ? deg[base + 3] : 0;
  int sum = v0 + v1 + v2 + v3;
  s[t] = sum;
  __syncthreads();
  for (int off = 1; off < 256; off <<= 1) {
    int xv = (t >= off) ? s[t - off] : 0;
    __syncthreads();
    s[t] += xv;
    __syncthreads();
  }
  int excl = s[t] - sum;
  int a0 = excl + v0, a1 = a0 + v1, a2 = a1 + v2, a3 = a2 + v3;
  if (base + 0 < n) incl[base + 0] = a0;
  if (base + 1 < n) incl[base + 1] = a1;
  if (base + 2 < n) incl[base + 2] = a2;
  if (base + 3 < n) incl[base + 3] = a3;
  if (t == 255) bsum[blockIdx.x] = s[255];
}

__global__ void k_scan2(int* bsum, int nb) {
  if (threadIdx.x == 0 && blockIdx.x == 0) {
    int acc = 0;
    for (int i = 0; i < nb; ++i) { int v = bsum[i]; bsum[i] = acc; acc += v; }
  }
}

__global__ __launch_bounds__(256) void k_scan3(
    const int* __restrict__ incl, const int* __restrict__ bsum,
    int* __restrict__ rowptr, int n) {
  int i = blockIdx.x * 256 + threadIdx.x;
  if (i < n) rowptr[i + 1] = incl[i] + bsum[i >> 10];
  if (i == 0) rowptr[0] = 0;
}

// ---------------- edge placement into CSR order -----------------------------
__global__ __launch_bounds__(256) void k_place(
    const int* __restrict__ ei, int* __restrict__ cursor,
    int* __restrict__ ssrc, int E, int n) {
  int e = blockIdx.x * 256 + threadIdx.x;
  if (e >= E) return;
  int s = ei[e], d = ei[E + e];
  if ((unsigned)d >= (unsigned)n) return;
  int pos = atomicAdd(&cursor[d], 1);
  ssrc[pos] = s;
}

// ------- gather-mean layer 1 (bf16 in, bf16 out), 4x-unrolled MLP -----------
__global__ __launch_bounds__(256) void k_agg1(
    const int* __restrict__ rowptr, const int* __restrict__ ssrc,
    const unsigned short* __restrict__ xbf, unsigned short* __restrict__ aggbf,
    int n) {
  int w = (blockIdx.x * 256 + threadIdx.x) >> 6;  // wave -> node
  int l = threadIdx.x & 63;                       // lane -> 2 channels
  if (w >= n) return;
  int beg = rowptr[w], end = rowptr[w + 1];
  float ax = 0.f, ay = 0.f;
  const unsigned* xb = (const unsigned*)xbf;
  int p = beg;
  for (; p + 4 <= end; p += 4) {
    int s0 = ssrc[p + 0], s1 = ssrc[p + 1];
    int s2 = ssrc[p + 2], s3 = ssrc[p + 3];
    unsigned v0 = xb[(size_t)s0 * 64 + l];
    unsigned v1 = xb[(size_t)s1 * 64 + l];
    unsigned v2 = xb[(size_t)s2 * 64 + l];
    unsigned v3 = xb[(size_t)s3 * 64 + l];
    ax += bf2f((unsigned short)v0) + bf2f((unsigned short)v1)
        + bf2f((unsigned short)v2) + bf2f((unsigned short)v3);
    ay += bf2f((unsigned short)(v0 >> 16)) + bf2f((unsigned short)(v1 >> 16))
        + bf2f((unsigned short)(v2 >> 16)) + bf2f((unsigned short)(v3 >> 16));
  }
  for (; p < end; ++p) {
    unsigned v = xb[(size_t)ssrc[p] * 64 + l];
    ax += bf2f((unsigned short)v);
    ay += bf2f((unsigned short)(v >> 16));
  }
  float inv = 1.0f / fmaxf((float)(end - beg), 1.0f);
  unsigned o = ((unsigned)(unsigned short)f2bf(ay * inv) << 16)
             | (unsigned short)f2bf(ax * inv);
  ((unsigned*)aggbf)[(size_t)w * 64 + l] = o;
}

// ------------- weight packing into MFMA B-fragment order --------------------
__global__ __launch_bounds__(256) void k_pack1(
    const float* __restrict__ Wl, const float* __restrict__ Wr,
    short* __restrict__ dst) {
  int t = blockIdx.x * 256 + threadIdx.x;  // 64 frags * 64 lanes
  if (t >= 64 * 64) return;
  int l = t & 63, f = t >> 6;
  int kt = f >> 3, ct = f & 7;
  int c = ct * 16 + (l & 15);
  int kb = kt * 32 + (l >> 4) * 8;
  short8 v;
#pragma unroll
  for (int j = 0; j < 8; ++j) {
    int k = kb + j;
    float w = (k < 128) ? Wl[k * 128 + c] : Wr[(k - 128) * 128 + c];
    v[j] = f2bf(w);
  }
  *(short8*)(dst + (size_t)t * 8) = v;
}

__global__ __launch_bounds__(256) void k_pack2(
    const float* __restrict__ Wl, const float* __restrict__ Wr,
    short* __restrict__ dst) {
  int t = blockIdx.x * 256 + threadIdx.x;  // 32 frags * 64 lanes
  if (t >= 32 * 64) return;
  int l = t & 63, f = t >> 6;
  int kt = f >> 3, ct = f & 7;
  int c = ct * 16 + (l & 15);
  int kb = kt * 32 + (l >> 4) * 8;
  short8 v;
#pragma unroll
  for (int j = 0; j < 8; ++j) {
    int k = kb + j;
    float w = (c < 64) ? Wl[k * 64 + c] : Wr[k * 64 + (c - 64)];
    v[j] = f2bf(w);
  }
  *(short8*)(dst + (size_t)t * 8) = v;
}

// ------------- layer 1 MFMA: h1 = relu(bn1([agg|x] @ Wcat1 + b1)) -----------
__global__ __launch_bounds__(256) void k_lin1(
    const unsigned short* __restrict__ xbf,
    const unsigned short* __restrict__ aggbf,
    const short* __restrict__ wp, const float* __restrict__ b,
    const float* __restrict__ g, const float* __restrict__ be,
    unsigned short* __restrict__ h1bf, int n) {
  __shared__ short As[64 * 256];  // 64 rows x 256 k, bf16, XOR-swizzled, 32 KB
  int tid = threadIdx.x;
  int row0 = blockIdx.x * 64;
#pragma unroll
  for (int it = 0; it < 8; ++it) {
    int slot = it * 256 + tid;     // 0..2047 16B chunks
    int r = slot >> 5;             // row 0..63
    int c16 = slot & 31;           // chunk (8 bf16); <16: agg half, else x half
    int gr = row0 + r;
    short8 o = {0, 0, 0, 0, 0, 0, 0, 0};
    if (gr < n) {
      const unsigned short* src = (c16 < 16)
          ? (aggbf + (size_t)gr * 128 + c16 * 8)
          : (xbf + (size_t)gr * 128 + (c16 - 16) * 8);
      o = *(const short8*)src;
    }
    int byte = r * 512 + ((c16 * 16) ^ ((r & 7) << 4));
    *(short8*)((char*)As + byte) = o;
  }
  __syncthreads();
  int w = tid >> 6, l = tid & 63;
  int rloc = w * 16 + (l & 15);
  f32x4 acc[8];
#pragma unroll
  for (int i = 0; i < 8; ++i) acc[i] = (f32x4){0.f, 0.f, 0.f, 0.f};
#pragma unroll
  for (int kt = 0; kt < 8; ++kt) {
    int abyte = rloc * 512 + ((kt * 64 + (l >> 4) * 16) ^ ((rloc & 7) << 4));
    short8 a = *(short8*)((char*)As + abyte);
#pragma unroll
    for (int ct = 0; ct < 8; ++ct) {
      short8 bf = *(const short8*)(wp + ((size_t)((kt * 8 + ct) * 64 + l)) * 8);
      acc[ct] = __builtin_amdgcn_mfma_f32_16x16x32_bf16(a, bf, acc[ct], 0, 0, 0);
    }
  }
  // epilogue: C/D layout col=lane&15, row=(lane>>4)*4+q
  int rbase = row0 + w * 16 + (l >> 4) * 4;
  int cb = l & 15;
#pragma unroll
  for (int ct = 0; ct < 8; ++ct) {
    int c = ct * 16 + cb;
    float sc = g[c] * (1.0f / sqrtf(1.0f + EPS));
    float bb = b[c], bt = be[c];
#pragma unroll
    for (int q = 0; q < 4; ++q) {
      int r = rbase + q;
      if (r < n) {
        float v = (acc[ct][q] + bb) * sc + bt;
        h1bf[(size_t)r * 128 + c] = (unsigned short)f2bf(fmaxf(v, 0.f));
      }
    }
  }
}

// ------- layer 2 MFMA: [y(bf16) | pre(f32,d_out)] = h1 @ Wcat2 + [0|b2] -----
__global__ __launch_bounds__(256) void k_lin2(
    const unsigned short* __restrict__ h1bf, const short* __restrict__ wp,
    const float* __restrict__ b2,
    unsigned short* __restrict__ ybf, float* __restrict__ pre, int n) {
  __shared__ short As[64 * 128];  // 16 KB
  int tid = threadIdx.x;
  int row0 = blockIdx.x * 64;
#pragma unroll
  for (int it = 0; it < 4; ++it) {
    int slot = it * 256 + tid;     // 0..1023
    int r = slot >> 4;             // row 0..63
    int c16 = slot & 15;
    int gr = row0 + r;
    short8 o = {0, 0, 0, 0, 0, 0, 0, 0};
    if (gr < n) o = *(const short8*)(h1bf + (size_t)gr * 128 + c16 * 8);
    int byte = r * 256 + ((c16 * 16) ^ ((r & 7) << 4));
    *(short8*)((char*)As + byte) = o;
  }
  __syncthreads();
  int w = tid >> 6, l = tid & 63;
  int rloc = w * 16 + (l & 15);
  f32x4 acc[8];
#pragma unroll
  for (int i = 0; i < 8; ++i) acc[i] = (f32x4){0.f, 0.f, 0.f, 0.f};
#pragma unroll
  for (int kt = 0; kt < 4; ++kt) {
    int abyte = rloc * 256 + ((kt * 64 + (l >> 4) * 16) ^ ((rloc & 7) << 4));
    short8 a = *(short8*)((char*)As + abyte);
#pragma unroll
    for (int ct = 0; ct < 8; ++ct) {
      short8 bf = *(const short8*)(wp + ((size_t)((kt * 8 + ct) * 64 + l)) * 8);
      acc[ct] = __builtin_amdgcn_mfma_f32_16x16x32_bf16(a, bf, acc[ct], 0, 0, 0);
    }
  }
  int rbase = row0 + w * 16 + (l >> 4) * 4;
  int cb = l & 15;
#pragma unroll
  for (int ct = 0; ct < 8; ++ct) {
    int c = ct * 16 + cb;
#pragma unroll
    for (int q = 0; q < 4; ++q) {
      int r = rbase + q;
      if (r < n) {
        if (c < 64) ybf[(size_t)r * 64 + c] = (unsigned short)f2bf(acc[ct][q]);
        else        pre[(size_t)r * 64 + (c - 64)] = acc[ct][q] + b2[c - 64];
      }
    }
  }
}

// ------ gather-mean layer 2 fused with final BN+ReLU, 4x-unrolled -----------
__global__ __launch_bounds__(256) void k_agg2(
    const int* __restrict__ rowptr, const int* __restrict__ ssrc,
    const unsigned short* __restrict__ ybf, const float* __restrict__ g,
    const float* __restrict__ be, float* __restrict__ out, int n) {
  int w = (blockIdx.x * 256 + threadIdx.x) >> 6;  // wave -> node
  int l = threadIdx.x & 63;                       // lane -> channel
  if (w >= n) return;
  int beg = rowptr[w], end = rowptr[w + 1];
  float acc = 0.f;
  int p = beg;
  for (; p + 4 <= end; p += 4) {
    int s0 = ssrc[p + 0], s1 = ssrc[p + 1];
    int s2 = ssrc[p + 2], s3 = ssrc[p + 3];
    unsigned short v0 = ybf[(size_t)s0 * 64 + l];
    unsigned short v1 = ybf[(size_t)s1 * 64 + l];
    unsigned short v2 = ybf[(size_t)s2 * 64 + l];
    unsigned short v3 = ybf[(size_t)s3 * 64 + l];
    acc += bf2f(v0) + bf2f(v1) + bf2f(v2) + bf2f(v3);
  }
  for (; p < end; ++p) acc += bf2f(ybf[(size_t)ssrc[p] * 64 + l]);
  float inv = 1.0f / fmaxf((float)(end - beg), 1.0f);
  float sc = g[l] * (1.0f / sqrtf(1.0f + EPS));
  size_t o = (size_t)w * 64 + l;
  float v = (acc * inv + out[o]) * sc + be[l];
  out[o] = fmaxf(v, 0.f);
}

extern "C" void kernel_launch(void* const* d_in, const int* in_sizes, int n_in,
                              void* d_out, int out_size, void* d_ws, size_t ws_size,
                              hipStream_t stream) {
  const float* x   = (const float*)d_in[0];
  const int*   ei  = (const int*)d_in[1];
  const float* W1l = (const float*)d_in[2];
  const float* b1  = (const float*)d_in[3];
  const float* W1r = (const float*)d_in[4];
  const float* g1  = (const float*)d_in[5];
  const float* be1 = (const float*)d_in[6];
  const float* W2l = (const float*)d_in[7];
  const float* b2  = (const float*)d_in[8];
  const float* W2r = (const float*)d_in[9];
  const float* g2  = (const float*)d_in[10];
  const float* be2 = (const float*)d_in[11];
  float* out = (float*)d_out;

  int n = in_sizes[0] / 128;
  int E = in_sizes[1] / 2;
  int nb = (n + 1023) / 1024;

  // workspace carve-up (aligned to 256B)
  char* ws = (char*)d_ws;
  size_t o = 0;
  auto carve = [&](size_t bytes) {
    char* p = ws + o;
    o += (bytes + 255) & ~(size_t)255;
    return p;
  };
  int*   deg    = (int*)carve((size_t)n * 4);
  int*   rowptr = (int*)carve((size_t)(n + 1) * 4);
  int*   cursor = (int*)carve((size_t)n * 4);
  int*   incl   = (int*)carve((size_t)n * 4);
  int*   bsum   = (int*)carve((size_t)nb * 4);
  int*   ssrc   = (int*)carve((size_t)E * 4);
  short* wp1    = (short*)carve((size_t)64 * 64 * 8 * 2);    // 64 KB
  short* wp2    = (short*)carve((size_t)32 * 64 * 8 * 2);    // 32 KB
  unsigned short* xbf   = (unsigned short*)carve((size_t)n * 128 * 2);
  unsigned short* aggbf = (unsigned short*)carve((size_t)n * 128 * 2);
  unsigned short* h1bf  = (unsigned short*)carve((size_t)n * 128 * 2);
  unsigned short* ybf   = (unsigned short*)carve((size_t)n * 64 * 2);

  hipMemsetAsync(deg, 0, (size_t)n * 4, stream);

  k_deg<<<(E + 255) / 256, 256, 0, stream>>>(ei, deg, E, n);
  k_scan1<<<nb, 256, 0, stream>>>(deg, incl, bsum, n);
  k_scan2<<<1, 64, 0, stream>>>(bsum, nb);
  k_scan3<<<(n + 255) / 256, 256, 0, stream>>>(incl, bsum, rowptr, n);
  hipMemcpyAsync(cursor, rowptr, (size_t)n * 4, hipMemcpyDeviceToDevice, stream);
  k_place<<<(E + 255) / 256, 256, 0, stream>>>(ei, cursor, ssrc, E, n);
  {
    long long n8 = (long long)n * 16;  // 16 chunks of 8 floats per row
    k_cast<<<(int)((n8 + 255) / 256), 256, 0, stream>>>(x, xbf, n8);
  }
  k_pack1<<<16, 256, 0, stream>>>(W1l, W1r, wp1);
  k_pack2<<<8, 256, 0, stream>>>(W2l, W2r, wp2);

  {
    long long T = (long long)n * 64;
    k_agg1<<<(int)((T + 255) / 256), 256, 0, stream>>>(rowptr, ssrc, xbf, aggbf, n);
  }
  k_lin1<<<(n + 63) / 64, 256, 0, stream>>>(xbf, aggbf, wp1, b1, g1, be1, h1bf, n);
  k_lin2<<<(n + 63) / 64, 256, 0, stream>>>(h1bf, wp2, b2, ybf, out, n);
  {
    long long T = (long long)n * 64;
    k_agg2<<<(int)((T + 255) / 256), 256, 0, stream>>>(rowptr, ssrc, ybf, g2, be2, out, n);
  }
}

// Round 5
// 276.801 us; speedup vs baseline: 15.8928x; 1.5638x over previous
//
#include <hip/hip_runtime.h>
#include <math.h>

#define EPS 1e-5f
#define BSH 9              // bucket = dst >> 9 (512 nodes per bucket)
#define BSPAN 512
#define CHUNK 2048         // edges per block in hist/scatter
#define CAP 16384          // LDS staging capacity in k_build

typedef __attribute__((ext_vector_type(8))) short short8;
typedef __attribute__((ext_vector_type(4))) float f32x4;

__device__ __forceinline__ short f2bf(float f) {
  union { float f; unsigned u; } v; v.f = f;
  unsigned r = v.u + 0x7fff + ((v.u >> 16) & 1);   // RNE
  return (short)(r >> 16);
}
__device__ __forceinline__ float bf2f(unsigned short u) {
  union { unsigned u; float f; } v; v.u = ((unsigned)u) << 16; return v.f;
}

// ---------------- fp32 -> bf16 cast (x) -------------------------------------
__global__ __launch_bounds__(256) void k_cast(
    const float* __restrict__ in, unsigned short* __restrict__ outb,
    long long n8) {
  long long i = (long long)blockIdx.x * 256 + threadIdx.x;
  if (i >= n8) return;
  const float4* p = (const float4*)in + i * 2;
  float4 v0 = p[0], v1 = p[1];
  short8 o;
  o[0] = f2bf(v0.x); o[1] = f2bf(v0.y); o[2] = f2bf(v0.z); o[3] = f2bf(v0.w);
  o[4] = f2bf(v1.x); o[5] = f2bf(v1.y); o[6] = f2bf(v1.z); o[7] = f2bf(v1.w);
  ((short8*)outb)[i] = o;
}

// ---------------- CSR build pass 1: coarse bucket histogram -----------------
__global__ __launch_bounds__(256) void k_hist(
    const int* __restrict__ ei, int* __restrict__ bcnt, int E, int n) {
  __shared__ int h[256];
  int tid = threadIdx.x;
  h[tid] = 0;
  __syncthreads();
  long long base = (long long)blockIdx.x * CHUNK;
#pragma unroll
  for (int i = 0; i < CHUNK / 256; ++i) {
    long long e = base + i * 256 + tid;
    if (e < E) {
      int d = ei[E + e];
      if ((unsigned)d < (unsigned)n) atomicAdd(&h[d >> BSH], 1);
    }
  }
  __syncthreads();
  if (h[tid]) atomicAdd(&bcnt[tid], h[tid]);
}

// ---------------- CSR build pass 2: scan bucket counts ----------------------
__global__ __launch_bounds__(256) void k_bscan(
    const int* __restrict__ bcnt, int* __restrict__ bbase,
    int* __restrict__ bcur, int nbk) {
  __shared__ int s[256];
  int t = threadIdx.x;
  int v = (t < nbk) ? bcnt[t] : 0;
  s[t] = v;
  __syncthreads();
  for (int off = 1; off < 256; off <<= 1) {
    int xv = (t >= off) ? s[t - off] : 0;
    __syncthreads();
    s[t] += xv;
    __syncthreads();
  }
  int excl = s[t] - v;
  if (t < nbk) { bbase[t] = excl; bcur[t] = excl; }
}

// ---------------- CSR build pass 3: partition edges into buckets ------------
// epk[pos] = (dst_local << 18) | src   (n < 2^18)
__global__ __launch_bounds__(256) void k_scatter(
    const int* __restrict__ ei, int* __restrict__ bcur,
    unsigned* __restrict__ epk, int E, int n) {
  __shared__ int h[256];
  __shared__ int base[256];
  int tid = threadIdx.x;
  h[tid] = 0;
  __syncthreads();
  long long cbase = (long long)blockIdx.x * CHUNK;
  int src[CHUNK / 256], dl[CHUNK / 256], rk[CHUNK / 256], bk[CHUNK / 256];
#pragma unroll
  for (int i = 0; i < CHUNK / 256; ++i) {
    long long e = cbase + i * 256 + tid;
    bk[i] = -1;
    if (e < E) {
      int s = ei[e], d = ei[E + e];
      if ((unsigned)d < (unsigned)n) {
        bk[i] = d >> BSH; dl[i] = d & (BSPAN - 1); src[i] = s;
        rk[i] = atomicAdd(&h[bk[i]], 1);
      }
    }
  }
  __syncthreads();
  base[tid] = h[tid] ? atomicAdd(&bcur[tid], h[tid]) : 0;
  __syncthreads();
#pragma unroll
  for (int i = 0; i < CHUNK / 256; ++i) {
    if (bk[i] >= 0)
      epk[base[bk[i]] + rk[i]] = ((unsigned)dl[i] << 18) | (unsigned)src[i];
  }
}

// ------- CSR build pass 4: per-bucket local sort -> rowptr + ssrc -----------
__global__ __launch_bounds__(256) void k_build(
    const unsigned* __restrict__ epk, const int* __restrict__ bbase,
    const int* __restrict__ bcnt, int* __restrict__ rowptr,
    int* __restrict__ ssrc, int n, int nbk) {
  __shared__ int cnt[BSPAN];
  __shared__ int rp[BSPAN];
  __shared__ int cur[BSPAN];
  __shared__ int lsrc[CAP];
  int b = blockIdx.x, t = threadIdx.x;
  int segbase = bbase[b], segcnt = bcnt[b];
  int i0 = t, i1 = t + 256;
  cnt[i0] = 0; cnt[i1] = 0;
  __syncthreads();
  for (int i = t; i < segcnt; i += 256)
    atomicAdd(&cnt[epk[segbase + i] >> 18], 1);
  __syncthreads();
  rp[i0] = cnt[i0]; rp[i1] = cnt[i1];
  __syncthreads();
  for (int off = 1; off < BSPAN; off <<= 1) {
    int v0 = (i0 >= off) ? rp[i0 - off] : 0;
    int v1 = (i1 >= off) ? rp[i1 - off] : 0;
    __syncthreads();
    rp[i0] += v0; rp[i1] += v1;
    __syncthreads();
  }
  int e0 = rp[i0] - cnt[i0], e1 = rp[i1] - cnt[i1];
  cur[i0] = e0; cur[i1] = e1;
  int node0 = b * BSPAN;
  if (node0 + i0 < n) rowptr[node0 + i0] = segbase + e0;
  if (node0 + i1 < n) rowptr[node0 + i1] = segbase + e1;
  if (b == nbk - 1 && t == 0) rowptr[n] = segbase + segcnt;
  __syncthreads();
  if (segcnt <= CAP) {
    for (int i = t; i < segcnt; i += 256) {
      unsigned k = epk[segbase + i];
      int pos = atomicAdd(&cur[k >> 18], 1);
      lsrc[pos] = (int)(k & 0x3FFFFu);
    }
    __syncthreads();
    for (int i = t; i < segcnt; i += 256) ssrc[segbase + i] = lsrc[i];
  } else {
    for (int i = t; i < segcnt; i += 256) {
      unsigned k = epk[segbase + i];
      int pos = atomicAdd(&cur[k >> 18], 1);
      ssrc[segbase + pos] = (int)(k & 0x3FFFFu);
    }
  }
}

// ------- gather-mean layer 1 (bf16 in, bf16 out), 4x-unrolled MLP -----------
__global__ __launch_bounds__(256) void k_agg1(
    const int* __restrict__ rowptr, const int* __restrict__ ssrc,
    const unsigned short* __restrict__ xbf, unsigned short* __restrict__ aggbf,
    int n) {
  int w = (blockIdx.x * 256 + threadIdx.x) >> 6;  // wave -> node
  int l = threadIdx.x & 63;                       // lane -> 2 channels
  if (w >= n) return;
  int beg = rowptr[w], end = rowptr[w + 1];
  float ax = 0.f, ay = 0.f;
  const unsigned* xb = (const unsigned*)xbf;
  int p = beg;
  for (; p + 4 <= end; p += 4) {
    int s0 = ssrc[p + 0], s1 = ssrc[p + 1];
    int s2 = ssrc[p + 2], s3 = ssrc[p + 3];
    unsigned v0 = xb[(size_t)s0 * 64 + l];
    unsigned v1 = xb[(size_t)s1 * 64 + l];
    unsigned v2 = xb[(size_t)s2 * 64 + l];
    unsigned v3 = xb[(size_t)s3 * 64 + l];
    ax += bf2f((unsigned short)v0) + bf2f((unsigned short)v1)
        + bf2f((unsigned short)v2) + bf2f((unsigned short)v3);
    ay += bf2f((unsigned short)(v0 >> 16)) + bf2f((unsigned short)(v1 >> 16))
        + bf2f((unsigned short)(v2 >> 16)) + bf2f((unsigned short)(v3 >> 16));
  }
  for (; p < end; ++p) {
    unsigned v = xb[(size_t)ssrc[p] * 64 + l];
    ax += bf2f((unsigned short)v);
    ay += bf2f((unsigned short)(v >> 16));
  }
  float inv = 1.0f / fmaxf((float)(end - beg), 1.0f);
  unsigned o = ((unsigned)(unsigned short)f2bf(ay * inv) << 16)
             | (unsigned short)f2bf(ax * inv);
  ((unsigned*)aggbf)[(size_t)w * 64 + l] = o;
}

// ------------- weight packing into MFMA B-fragment order --------------------
__global__ __launch_bounds__(256) void k_pack1(
    const float* __restrict__ Wl, const float* __restrict__ Wr,
    short* __restrict__ dst) {
  int t = blockIdx.x * 256 + threadIdx.x;  // 64 frags * 64 lanes
  if (t >= 64 * 64) return;
  int l = t & 63, f = t >> 6;
  int kt = f >> 3, ct = f & 7;
  int c = ct * 16 + (l & 15);
  int kb = kt * 32 + (l >> 4) * 8;
  short8 v;
#pragma unroll
  for (int j = 0; j < 8; ++j) {
    int k = kb + j;
    float w = (k < 128) ? Wl[k * 128 + c] : Wr[(k - 128) * 128 + c];
    v[j] = f2bf(w);
  }
  *(short8*)(dst + (size_t)t * 8) = v;
}

__global__ __launch_bounds__(256) void k_pack2(
    const float* __restrict__ Wl, const float* __restrict__ Wr,
    short* __restrict__ dst) {
  int t = blockIdx.x * 256 + threadIdx.x;  // 32 frags * 64 lanes
  if (t >= 32 * 64) return;
  int l = t & 63, f = t >> 6;
  int kt = f >> 3, ct = f & 7;
  int c = ct * 16 + (l & 15);
  int kb = kt * 32 + (l >> 4) * 8;
  short8 v;
#pragma unroll
  for (int j = 0; j < 8; ++j) {
    int k = kb + j;
    float w = (c < 64) ? Wl[k * 64 + c] : Wr[k * 64 + (c - 64)];
    v[j] = f2bf(w);
  }
  *(short8*)(dst + (size_t)t * 8) = v;
}

// ------------- layer 1 MFMA: h1 = relu(bn1([agg|x] @ Wcat1 + b1)) -----------
__global__ __launch_bounds__(256) void k_lin1(
    const unsigned short* __restrict__ xbf,
    const unsigned short* __restrict__ aggbf,
    const short* __restrict__ wp, const float* __restrict__ b,
    const float* __restrict__ g, const float* __restrict__ be,
    unsigned short* __restrict__ h1bf, int n) {
  __shared__ short As[64 * 256];  // 64 rows x 256 k, bf16, XOR-swizzled, 32 KB
  int tid = threadIdx.x;
  int row0 = blockIdx.x * 64;
#pragma unroll
  for (int it = 0; it < 8; ++it) {
    int slot = it * 256 + tid;     // 0..2047 16B chunks
    int r = slot >> 5;             // row 0..63
    int c16 = slot & 31;           // chunk (8 bf16); <16: agg half, else x half
    int gr = row0 + r;
    short8 o = {0, 0, 0, 0, 0, 0, 0, 0};
    if (gr < n) {
      const unsigned short* src = (c16 < 16)
          ? (aggbf + (size_t)gr * 128 + c16 * 8)
          : (xbf + (size_t)gr * 128 + (c16 - 16) * 8);
      o = *(const short8*)src;
    }
    int byte = r * 512 + ((c16 * 16) ^ ((r & 7) << 4));
    *(short8*)((char*)As + byte) = o;
  }
  __syncthreads();
  int w = tid >> 6, l = tid & 63;
  int rloc = w * 16 + (l & 15);
  f32x4 acc[8];
#pragma unroll
  for (int i = 0; i < 8; ++i) acc[i] = (f32x4){0.f, 0.f, 0.f, 0.f};
#pragma unroll
  for (int kt = 0; kt < 8; ++kt) {
    int abyte = rloc * 512 + ((kt * 64 + (l >> 4) * 16) ^ ((rloc & 7) << 4));
    short8 a = *(short8*)((char*)As + abyte);
#pragma unroll
    for (int ct = 0; ct < 8; ++ct) {
      short8 bf = *(const short8*)(wp + ((size_t)((kt * 8 + ct) * 64 + l)) * 8);
      acc[ct] = __builtin_amdgcn_mfma_f32_16x16x32_bf16(a, bf, acc[ct], 0, 0, 0);
    }
  }
  // epilogue: C/D layout col=lane&15, row=(lane>>4)*4+q
  int rbase = row0 + w * 16 + (l >> 4) * 4;
  int cb = l & 15;
#pragma unroll
  for (int ct = 0; ct < 8; ++ct) {
    int c = ct * 16 + cb;
    float sc = g[c] * (1.0f / sqrtf(1.0f + EPS));
    float bb = b[c], bt = be[c];
#pragma unroll
    for (int q = 0; q < 4; ++q) {
      int r = rbase + q;
      if (r < n) {
        float v = (acc[ct][q] + bb) * sc + bt;
        h1bf[(size_t)r * 128 + c] = (unsigned short)f2bf(fmaxf(v, 0.f));
      }
    }
  }
}

// ------- layer 2 MFMA: [y(bf16) | pre(f32,d_out)] = h1 @ Wcat2 + [0|b2] -----
__global__ __launch_bounds__(256) void k_lin2(
    const unsigned short* __restrict__ h1bf, const short* __restrict__ wp,
    const float* __restrict__ b2,
    unsigned short* __restrict__ ybf, float* __restrict__ pre, int n) {
  __shared__ short As[64 * 128];  // 16 KB
  int tid = threadIdx.x;
  int row0 = blockIdx.x * 64;
#pragma unroll
  for (int it = 0; it < 4; ++it) {
    int slot = it * 256 + tid;     // 0..1023
    int r = slot >> 4;             // row 0..63
    int c16 = slot & 15;
    int gr = row0 + r;
    short8 o = {0, 0, 0, 0, 0, 0, 0, 0};
    if (gr < n) o = *(const short8*)(h1bf + (size_t)gr * 128 + c16 * 8);
    int byte = r * 256 + ((c16 * 16) ^ ((r & 7) << 4));
    *(short8*)((char*)As + byte) = o;
  }
  __syncthreads();
  int w = tid >> 6, l = tid & 63;
  int rloc = w * 16 + (l & 15);
  f32x4 acc[8];
#pragma unroll
  for (int i = 0; i < 8; ++i) acc[i] = (f32x4){0.f, 0.f, 0.f, 0.f};
#pragma unroll
  for (int kt = 0; kt < 4; ++kt) {
    int abyte = rloc * 256 + ((kt * 64 + (l >> 4) * 16) ^ ((rloc & 7) << 4));
    short8 a = *(short8*)((char*)As + abyte);
#pragma unroll
    for (int ct = 0; ct < 8; ++ct) {
      short8 bf = *(const short8*)(wp + ((size_t)((kt * 8 + ct) * 64 + l)) * 8);
      acc[ct] = __builtin_amdgcn_mfma_f32_16x16x32_bf16(a, bf, acc[ct], 0, 0, 0);
    }
  }
  int rbase = row0 + w * 16 + (l >> 4) * 4;
  int cb = l & 15;
#pragma unroll
  for (int ct = 0; ct < 8; ++ct) {
    int c = ct * 16 + cb;
#pragma unroll
    for (int q = 0; q < 4; ++q) {
      int r = rbase + q;
      if (r < n) {
        if (c < 64) ybf[(size_t)r * 64 + c] = (unsigned short)f2bf(acc[ct][q]);
        else        pre[(size_t)r * 64 + (c - 64)] = acc[ct][q] + b2[c - 64];
      }
    }
  }
}

// ------ gather-mean layer 2 fused with final BN+ReLU, 4x-unrolled -----------
__global__ __launch_bounds__(256) void k_agg2(
    const int* __restrict__ rowptr, const int* __restrict__ ssrc,
    const unsigned short* __restrict__ ybf, const float* __restrict__ g,
    const float* __restrict__ be, float* __restrict__ out, int n) {
  int w = (blockIdx.x * 256 + threadIdx.x) >> 6;  // wave -> node
  int l = threadIdx.x & 63;                       // lane -> channel
  if (w >= n) return;
  int beg = rowptr[w], end = rowptr[w + 1];
  float acc = 0.f;
  int p = beg;
  for (; p + 4 <= end; p += 4) {
    int s0 = ssrc[p + 0], s1 = ssrc[p + 1];
    int s2 = ssrc[p + 2], s3 = ssrc[p + 3];
    unsigned short v0 = ybf[(size_t)s0 * 64 + l];
    unsigned short v1 = ybf[(size_t)s1 * 64 + l];
    unsigned short v2 = ybf[(size_t)s2 * 64 + l];
    unsigned short v3 = ybf[(size_t)s3 * 64 + l];
    acc += bf2f(v0) + bf2f(v1) + bf2f(v2) + bf2f(v3);
  }
  for (; p < end; ++p) acc += bf2f(ybf[(size_t)ssrc[p] * 64 + l]);
  float inv = 1.0f / fmaxf((float)(end - beg), 1.0f);
  float sc = g[l] * (1.0f / sqrtf(1.0f + EPS));
  size_t o = (size_t)w * 64 + l;
  float v = (acc * inv + out[o]) * sc + be[l];
  out[o] = fmaxf(v, 0.f);
}

extern "C" void kernel_launch(void* const* d_in, const int* in_sizes, int n_in,
                              void* d_out, int out_size, void* d_ws, size_t ws_size,
                              hipStream_t stream) {
  const float* x   = (const float*)d_in[0];
  const int*   ei  = (const int*)d_in[1];
  const float* W1l = (const float*)d_in[2];
  const float* b1  = (const float*)d_in[3];
  const float* W1r = (const float*)d_in[4];
  const float* g1  = (const float*)d_in[5];
  const float* be1 = (const float*)d_in[6];
  const float* W2l = (const float*)d_in[7];
  const float* b2  = (const float*)d_in[8];
  const float* W2r = (const float*)d_in[9];
  const float* g2  = (const float*)d_in[10];
  const float* be2 = (const float*)d_in[11];
  float* out = (float*)d_out;

  int n = in_sizes[0] / 128;
  int E = in_sizes[1] / 2;
  int nbk = (n + BSPAN - 1) / BSPAN;   // 196 for n=100000 (fits 256)
  int nce = (int)(((long long)E + CHUNK - 1) / CHUNK);

  // workspace carve-up (aligned to 256B)
  char* ws = (char*)d_ws;
  size_t o = 0;
  auto carve = [&](size_t bytes) {
    char* p = ws + o;
    o += (bytes + 255) & ~(size_t)255;
    return p;
  };
  int*      bcnt   = (int*)carve(256 * 4);
  int*      bbase  = (int*)carve(256 * 4);
  int*      bcur   = (int*)carve(256 * 4);
  unsigned* epk    = (unsigned*)carve((size_t)E * 4);
  int*      ssrc   = (int*)carve((size_t)E * 4);
  int*      rowptr = (int*)carve((size_t)(n + 1) * 4);
  short*    wp1    = (short*)carve((size_t)64 * 64 * 8 * 2);  // 64 KB
  short*    wp2    = (short*)carve((size_t)32 * 64 * 8 * 2);  // 32 KB
  unsigned short* xbf   = (unsigned short*)carve((size_t)n * 128 * 2);
  unsigned short* aggbf = (unsigned short*)carve((size_t)n * 128 * 2);
  unsigned short* h1bf  = (unsigned short*)carve((size_t)n * 128 * 2);
  unsigned short* ybf   = (unsigned short*)carve((size_t)n * 64 * 2);

  hipMemsetAsync(bcnt, 0, 256 * 4, stream);

  // CSR build: bucketed counting sort (no large random atomics)
  k_hist<<<nce, 256, 0, stream>>>(ei, bcnt, E, n);
  k_bscan<<<1, 256, 0, stream>>>(bcnt, bbase, bcur, nbk);
  k_scatter<<<nce, 256, 0, stream>>>(ei, bcur, epk, E, n);
  k_build<<<nbk, 256, 0, stream>>>(epk, bbase, bcnt, rowptr, ssrc, n, nbk);

  // independent prep
  {
    long long n8 = (long long)n * 16;  // 16 chunks of 8 floats per row
    k_cast<<<(int)((n8 + 255) / 256), 256, 0, stream>>>(x, xbf, n8);
  }
  k_pack1<<<16, 256, 0, stream>>>(W1l, W1r, wp1);
  k_pack2<<<8, 256, 0, stream>>>(W2l, W2r, wp2);

  {
    long long T = (long long)n * 64;
    k_agg1<<<(int)((T + 255) / 256), 256, 0, stream>>>(rowptr, ssrc, xbf, aggbf, n);
  }
  k_lin1<<<(n + 63) / 64, 256, 0, stream>>>(xbf, aggbf, wp1, b1, g1, be1, h1bf, n);
  k_lin2<<<(n + 63) / 64, 256, 0, stream>>>(h1bf, wp2, b2, ybf, out, n);
  {
    long long T = (long long)n * 64;
    k_agg2<<<(int)((T + 255) / 256), 256, 0, stream>>>(rowptr, ssrc, ybf, g2, be2, out, n);
  }
}

// Round 6
// 251.216 us; speedup vs baseline: 17.5113x; 1.1018x over previous
//
#include <hip/hip_runtime.h>
#include <math.h>

#define EPS 1e-5f
#define BSH 9              // bucket = dst >> 9 (512 nodes per bucket)
#define BSPAN 512
#define CHUNK 2048         // edges per block in hist/scatter
#define CAP 16384          // LDS staging capacity in k_build

typedef __attribute__((ext_vector_type(8))) short short8;
typedef __attribute__((ext_vector_type(4))) float f32x4;

__device__ __forceinline__ short f2bf(float f) {
  union { float f; unsigned u; } v; v.f = f;
  unsigned r = v.u + 0x7fff + ((v.u >> 16) & 1);   // RNE
  return (short)(r >> 16);
}
__device__ __forceinline__ float bf2f(unsigned short u) {
  union { unsigned u; float f; } v; v.u = ((unsigned)u) << 16; return v.f;
}

// ------- merged prep: x->bf16 cast | bucket histogram | weight packing ------
__global__ __launch_bounds__(256) void k_prep(
    const float* __restrict__ x, unsigned short* __restrict__ xbf, long long n8,
    const int* __restrict__ ei, int* __restrict__ bcnt, int E, int n,
    int ncast, int nhist,
    const float* __restrict__ W1l, const float* __restrict__ W1r,
    short* __restrict__ wp1,
    const float* __restrict__ W2l, const float* __restrict__ W2r,
    short* __restrict__ wp2) {
  __shared__ int h[256];
  int b = blockIdx.x, tid = threadIdx.x;
  if (b < ncast) {
    long long i = (long long)b * 256 + tid;
    if (i < n8) {
      const float4* p = (const float4*)x + i * 2;
      float4 v0 = p[0], v1 = p[1];
      short8 o;
      o[0] = f2bf(v0.x); o[1] = f2bf(v0.y); o[2] = f2bf(v0.z); o[3] = f2bf(v0.w);
      o[4] = f2bf(v1.x); o[5] = f2bf(v1.y); o[6] = f2bf(v1.z); o[7] = f2bf(v1.w);
      ((short8*)xbf)[i] = o;
    }
  } else if (b < ncast + nhist) {
    h[tid] = 0;
    __syncthreads();
    long long base = (long long)(b - ncast) * CHUNK;
#pragma unroll
    for (int i = 0; i < CHUNK / 256; ++i) {
      long long e = base + i * 256 + tid;
      if (e < E) {
        int d = ei[E + e];
        if ((unsigned)d < (unsigned)n) atomicAdd(&h[d >> BSH], 1);
      }
    }
    __syncthreads();
    if (h[tid]) atomicAdd(&bcnt[tid], h[tid]);
  } else if (b < ncast + nhist + 16) {
    int t = (b - ncast - nhist) * 256 + tid;   // 64 frags * 64 lanes
    int l = t & 63, f = t >> 6;
    int kt = f >> 3, ct = f & 7;
    int c = ct * 16 + (l & 15);
    int kb = kt * 32 + (l >> 4) * 8;
    short8 v;
#pragma unroll
    for (int j = 0; j < 8; ++j) {
      int k = kb + j;
      float w = (k < 128) ? W1l[k * 128 + c] : W1r[(k - 128) * 128 + c];
      v[j] = f2bf(w);
    }
    *(short8*)(wp1 + (size_t)t * 8) = v;
  } else {
    int t = (b - ncast - nhist - 16) * 256 + tid;  // 32 frags * 64 lanes
    int l = t & 63, f = t >> 6;
    int kt = f >> 3, ct = f & 7;
    int c = ct * 16 + (l & 15);
    int kb = kt * 32 + (l >> 4) * 8;
    short8 v;
#pragma unroll
    for (int j = 0; j < 8; ++j) {
      int k = kb + j;
      float w = (c < 64) ? W2l[k * 64 + c] : W2r[k * 64 + (c - 64)];
      v[j] = f2bf(w);
    }
    *(short8*)(wp2 + (size_t)t * 8) = v;
  }
}

// ---------------- CSR build pass 2: scan bucket counts ----------------------
__global__ __launch_bounds__(256) void k_bscan(
    const int* __restrict__ bcnt, int* __restrict__ bbase,
    int* __restrict__ bcur, int nbk) {
  __shared__ int s[256];
  int t = threadIdx.x;
  int v = (t < nbk) ? bcnt[t] : 0;
  s[t] = v;
  __syncthreads();
  for (int off = 1; off < 256; off <<= 1) {
    int xv = (t >= off) ? s[t - off] : 0;
    __syncthreads();
    s[t] += xv;
    __syncthreads();
  }
  int excl = s[t] - v;
  if (t < nbk) { bbase[t] = excl; bcur[t] = excl; }
}

// ---------------- CSR build pass 3: partition edges into buckets ------------
// epk[pos] = (dst_local << 18) | src   (n < 2^18)
__global__ __launch_bounds__(256) void k_scatter(
    const int* __restrict__ ei, int* __restrict__ bcur,
    unsigned* __restrict__ epk, int E, int n) {
  __shared__ int h[256];
  __shared__ int base[256];
  int tid = threadIdx.x;
  h[tid] = 0;
  __syncthreads();
  long long cbase = (long long)blockIdx.x * CHUNK;
  int src[CHUNK / 256], dl[CHUNK / 256], rk[CHUNK / 256], bk[CHUNK / 256];
#pragma unroll
  for (int i = 0; i < CHUNK / 256; ++i) {
    long long e = cbase + i * 256 + tid;
    bk[i] = -1;
    if (e < E) {
      int s = ei[e], d = ei[E + e];
      if ((unsigned)d < (unsigned)n) {
        bk[i] = d >> BSH; dl[i] = d & (BSPAN - 1); src[i] = s;
        rk[i] = atomicAdd(&h[bk[i]], 1);
      }
    }
  }
  __syncthreads();
  base[tid] = h[tid] ? atomicAdd(&bcur[tid], h[tid]) : 0;
  __syncthreads();
#pragma unroll
  for (int i = 0; i < CHUNK / 256; ++i) {
    if (bk[i] >= 0)
      epk[base[bk[i]] + rk[i]] = ((unsigned)dl[i] << 18) | (unsigned)src[i];
  }
}

// ------- CSR build pass 4: per-bucket local sort -> rowptr + ssrc -----------
__global__ __launch_bounds__(256) void k_build(
    const unsigned* __restrict__ epk, const int* __restrict__ bbase,
    const int* __restrict__ bcnt, int* __restrict__ rowptr,
    int* __restrict__ ssrc, int n, int nbk) {
  __shared__ int cnt[BSPAN];
  __shared__ int rp[BSPAN];
  __shared__ int cur[BSPAN];
  __shared__ int lsrc[CAP];
  int b = blockIdx.x, t = threadIdx.x;
  int segbase = bbase[b], segcnt = bcnt[b];
  int i0 = t, i1 = t + 256;
  cnt[i0] = 0; cnt[i1] = 0;
  __syncthreads();
  for (int i = t; i < segcnt; i += 256)
    atomicAdd(&cnt[epk[segbase + i] >> 18], 1);
  __syncthreads();
  rp[i0] = cnt[i0]; rp[i1] = cnt[i1];
  __syncthreads();
  for (int off = 1; off < BSPAN; off <<= 1) {
    int v0 = (i0 >= off) ? rp[i0 - off] : 0;
    int v1 = (i1 >= off) ? rp[i1 - off] : 0;
    __syncthreads();
    rp[i0] += v0; rp[i1] += v1;
    __syncthreads();
  }
  int e0 = rp[i0] - cnt[i0], e1 = rp[i1] - cnt[i1];
  cur[i0] = e0; cur[i1] = e1;
  int node0 = b * BSPAN;
  if (node0 + i0 < n) rowptr[node0 + i0] = segbase + e0;
  if (node0 + i1 < n) rowptr[node0 + i1] = segbase + e1;
  if (b == nbk - 1 && t == 0) rowptr[n] = segbase + segcnt;
  __syncthreads();
  if (segcnt <= CAP) {
    for (int i = t; i < segcnt; i += 256) {
      unsigned k = epk[segbase + i];
      int pos = atomicAdd(&cur[k >> 18], 1);
      lsrc[pos] = (int)(k & 0x3FFFFu);
    }
    __syncthreads();
    for (int i = t; i < segcnt; i += 256) ssrc[segbase + i] = lsrc[i];
  } else {
    for (int i = t; i < segcnt; i += 256) {
      unsigned k = epk[segbase + i];
      int pos = atomicAdd(&cur[k >> 18], 1);
      ssrc[segbase + pos] = (int)(k & 0x3FFFFu);
    }
  }
}

// ------- gather-mean layer 1: 2 edges/wave (32-lane halves), 4x MLP ---------
__global__ __launch_bounds__(256) void k_agg1(
    const int* __restrict__ rowptr, const int* __restrict__ ssrc,
    const unsigned* __restrict__ xbu, unsigned* __restrict__ aggu, int n) {
  int w = (blockIdx.x * 256 + threadIdx.x) >> 6;  // wave -> node
  if (w >= n) return;
  int l = threadIdx.x & 63;
  int lh = l & 31;          // uint2 chunk -> channels 4*lh .. 4*lh+3
  int hh = l >> 5;          // half-wave -> edge parity
  int beg = rowptr[w], end = rowptr[w + 1];
  float a0 = 0.f, a1 = 0.f, a2 = 0.f, a3 = 0.f;
  const uint2* xb2 = (const uint2*)xbu;
  int p = beg + hh;
  for (; p + 6 < end; p += 8) {
    int s0 = ssrc[p], s1 = ssrc[p + 2], s2 = ssrc[p + 4], s3 = ssrc[p + 6];
    uint2 v0 = xb2[(size_t)s0 * 32 + lh];
    uint2 v1 = xb2[(size_t)s1 * 32 + lh];
    uint2 v2 = xb2[(size_t)s2 * 32 + lh];
    uint2 v3 = xb2[(size_t)s3 * 32 + lh];
    a0 += bf2f((unsigned short)v0.x) + bf2f((unsigned short)v1.x)
        + bf2f((unsigned short)v2.x) + bf2f((unsigned short)v3.x);
    a1 += bf2f((unsigned short)(v0.x >> 16)) + bf2f((unsigned short)(v1.x >> 16))
        + bf2f((unsigned short)(v2.x >> 16)) + bf2f((unsigned short)(v3.x >> 16));
    a2 += bf2f((unsigned short)v0.y) + bf2f((unsigned short)v1.y)
        + bf2f((unsigned short)v2.y) + bf2f((unsigned short)v3.y);
    a3 += bf2f((unsigned short)(v0.y >> 16)) + bf2f((unsigned short)(v1.y >> 16))
        + bf2f((unsigned short)(v2.y >> 16)) + bf2f((unsigned short)(v3.y >> 16));
  }
  for (; p < end; p += 2) {
    uint2 v = xb2[(size_t)ssrc[p] * 32 + lh];
    a0 += bf2f((unsigned short)v.x);
    a1 += bf2f((unsigned short)(v.x >> 16));
    a2 += bf2f((unsigned short)v.y);
    a3 += bf2f((unsigned short)(v.y >> 16));
  }
  a0 += __shfl_xor(a0, 32, 64);
  a1 += __shfl_xor(a1, 32, 64);
  a2 += __shfl_xor(a2, 32, 64);
  a3 += __shfl_xor(a3, 32, 64);
  if (hh == 0) {
    float inv = 1.0f / fmaxf((float)(end - beg), 1.0f);
    unsigned o0 = ((unsigned)(unsigned short)f2bf(a1 * inv) << 16)
                | (unsigned short)f2bf(a0 * inv);
    unsigned o1 = ((unsigned)(unsigned short)f2bf(a3 * inv) << 16)
                | (unsigned short)f2bf(a2 * inv);
    ((uint2*)aggu)[(size_t)w * 32 + lh] = make_uint2(o0, o1);
  }
}

// ------------- layer 1 MFMA: h1 = relu(bn1([agg|x] @ Wcat1 + b1)) -----------
__global__ __launch_bounds__(256) void k_lin1(
    const unsigned short* __restrict__ xbf,
    const unsigned short* __restrict__ aggbf,
    const short* __restrict__ wp, const float* __restrict__ b,
    const float* __restrict__ g, const float* __restrict__ be,
    unsigned short* __restrict__ h1bf, int n) {
  __shared__ short As[64 * 256];  // 64 rows x 256 k, bf16, XOR-swizzled, 32 KB
  int tid = threadIdx.x;
  int row0 = blockIdx.x * 64;
#pragma unroll
  for (int it = 0; it < 8; ++it) {
    int slot = it * 256 + tid;     // 0..2047 16B chunks
    int r = slot >> 5;             // row 0..63
    int c16 = slot & 31;           // chunk (8 bf16); <16: agg half, else x half
    int gr = row0 + r;
    short8 o = {0, 0, 0, 0, 0, 0, 0, 0};
    if (gr < n) {
      const unsigned short* src = (c16 < 16)
          ? (aggbf + (size_t)gr * 128 + c16 * 8)
          : (xbf + (size_t)gr * 128 + (c16 - 16) * 8);
      o = *(const short8*)src;
    }
    int byte = r * 512 + ((c16 * 16) ^ ((r & 7) << 4));
    *(short8*)((char*)As + byte) = o;
  }
  __syncthreads();
  int w = tid >> 6, l = tid & 63;
  int rloc = w * 16 + (l & 15);
  f32x4 acc[8];
#pragma unroll
  for (int i = 0; i < 8; ++i) acc[i] = (f32x4){0.f, 0.f, 0.f, 0.f};
#pragma unroll
  for (int kt = 0; kt < 8; ++kt) {
    int abyte = rloc * 512 + ((kt * 64 + (l >> 4) * 16) ^ ((rloc & 7) << 4));
    short8 a = *(short8*)((char*)As + abyte);
#pragma unroll
    for (int ct = 0; ct < 8; ++ct) {
      short8 bf = *(const short8*)(wp + ((size_t)((kt * 8 + ct) * 64 + l)) * 8);
      acc[ct] = __builtin_amdgcn_mfma_f32_16x16x32_bf16(a, bf, acc[ct], 0, 0, 0);
    }
  }
  // epilogue: C/D layout col=lane&15, row=(lane>>4)*4+q
  int rbase = row0 + w * 16 + (l >> 4) * 4;
  int cb = l & 15;
#pragma unroll
  for (int ct = 0; ct < 8; ++ct) {
    int c = ct * 16 + cb;
    float sc = g[c] * (1.0f / sqrtf(1.0f + EPS));
    float bb = b[c], bt = be[c];
#pragma unroll
    for (int q = 0; q < 4; ++q) {
      int r = rbase + q;
      if (r < n) {
        float v = (acc[ct][q] + bb) * sc + bt;
        h1bf[(size_t)r * 128 + c] = (unsigned short)f2bf(fmaxf(v, 0.f));
      }
    }
  }
}

// ------- layer 2 MFMA: [y(bf16) | pre(f32,d_out)] = h1 @ Wcat2 + [0|b2] -----
__global__ __launch_bounds__(256) void k_lin2(
    const unsigned short* __restrict__ h1bf, const short* __restrict__ wp,
    const float* __restrict__ b2,
    unsigned short* __restrict__ ybf, float* __restrict__ pre, int n) {
  __shared__ short As[64 * 128];  // 16 KB
  int tid = threadIdx.x;
  int row0 = blockIdx.x * 64;
#pragma unroll
  for (int it = 0; it < 4; ++it) {
    int slot = it * 256 + tid;     // 0..1023
    int r = slot >> 4;             // row 0..63
    int c16 = slot & 15;
    int gr = row0 + r;
    short8 o = {0, 0, 0, 0, 0, 0, 0, 0};
    if (gr < n) o = *(const short8*)(h1bf + (size_t)gr * 128 + c16 * 8);
    int byte = r * 256 + ((c16 * 16) ^ ((r & 7) << 4));
    *(short8*)((char*)As + byte) = o;
  }
  __syncthreads();
  int w = tid >> 6, l = tid & 63;
  int rloc = w * 16 + (l & 15);
  f32x4 acc[8];
#pragma unroll
  for (int i = 0; i < 8; ++i) acc[i] = (f32x4){0.f, 0.f, 0.f, 0.f};
#pragma unroll
  for (int kt = 0; kt < 4; ++kt) {
    int abyte = rloc * 256 + ((kt * 64 + (l >> 4) * 16) ^ ((rloc & 7) << 4));
    short8 a = *(short8*)((char*)As + abyte);
#pragma unroll
    for (int ct = 0; ct < 8; ++ct) {
      short8 bf = *(const short8*)(wp + ((size_t)((kt * 8 + ct) * 64 + l)) * 8);
      acc[ct] = __builtin_amdgcn_mfma_f32_16x16x32_bf16(a, bf, acc[ct], 0, 0, 0);
    }
  }
  int rbase = row0 + w * 16 + (l >> 4) * 4;
  int cb = l & 15;
#pragma unroll
  for (int ct = 0; ct < 8; ++ct) {
    int c = ct * 16 + cb;
#pragma unroll
    for (int q = 0; q < 4; ++q) {
      int r = rbase + q;
      if (r < n) {
        if (c < 64) ybf[(size_t)r * 64 + c] = (unsigned short)f2bf(acc[ct][q]);
        else        pre[(size_t)r * 64 + (c - 64)] = acc[ct][q] + b2[c - 64];
      }
    }
  }
}

// ------ gather-mean layer 2 + final BN+ReLU: 2 edges/wave, 4x MLP -----------
__global__ __launch_bounds__(256) void k_agg2(
    const int* __restrict__ rowptr, const int* __restrict__ ssrc,
    const unsigned* __restrict__ ybu, const float* __restrict__ g,
    const float* __restrict__ be, float* __restrict__ out, int n) {
  int w = (blockIdx.x * 256 + threadIdx.x) >> 6;  // wave -> node
  if (w >= n) return;
  int l = threadIdx.x & 63;
  int lh = l & 31;          // u32 chunk -> channels 2*lh, 2*lh+1
  int hh = l >> 5;          // half-wave -> edge parity
  int beg = rowptr[w], end = rowptr[w + 1];
  float a0 = 0.f, a1 = 0.f;
  int p = beg + hh;
  for (; p + 6 < end; p += 8) {
    int s0 = ssrc[p], s1 = ssrc[p + 2], s2 = ssrc[p + 4], s3 = ssrc[p + 6];
    unsigned v0 = ybu[(size_t)s0 * 32 + lh];
    unsigned v1 = ybu[(size_t)s1 * 32 + lh];
    unsigned v2 = ybu[(size_t)s2 * 32 + lh];
    unsigned v3 = ybu[(size_t)s3 * 32 + lh];
    a0 += bf2f((unsigned short)v0) + bf2f((unsigned short)v1)
        + bf2f((unsigned short)v2) + bf2f((unsigned short)v3);
    a1 += bf2f((unsigned short)(v0 >> 16)) + bf2f((unsigned short)(v1 >> 16))
        + bf2f((unsigned short)(v2 >> 16)) + bf2f((unsigned short)(v3 >> 16));
  }
  for (; p < end; p += 2) {
    unsigned v = ybu[(size_t)ssrc[p] * 32 + lh];
    a0 += bf2f((unsigned short)v);
    a1 += bf2f((unsigned short)(v >> 16));
  }
  a0 += __shfl_xor(a0, 32, 64);
  a1 += __shfl_xor(a1, 32, 64);
  if (hh == 0) {
    float inv = 1.0f / fmaxf((float)(end - beg), 1.0f);
    float r = 1.0f / sqrtf(1.0f + EPS);
    float2 g2 = ((const float2*)g)[lh];
    float2 be2 = ((const float2*)be)[lh];
    float2 po = ((float2*)out)[(size_t)w * 32 + lh];
    float v0 = (a0 * inv + po.x) * (g2.x * r) + be2.x;
    float v1 = (a1 * inv + po.y) * (g2.y * r) + be2.y;
    ((float2*)out)[(size_t)w * 32 + lh] = make_float2(fmaxf(v0, 0.f), fmaxf(v1, 0.f));
  }
}

extern "C" void kernel_launch(void* const* d_in, const int* in_sizes, int n_in,
                              void* d_out, int out_size, void* d_ws, size_t ws_size,
                              hipStream_t stream) {
  const float* x   = (const float*)d_in[0];
  const int*   ei  = (const int*)d_in[1];
  const float* W1l = (const float*)d_in[2];
  const float* b1  = (const float*)d_in[3];
  const float* W1r = (const float*)d_in[4];
  const float* g1  = (const float*)d_in[5];
  const float* be1 = (const float*)d_in[6];
  const float* W2l = (const float*)d_in[7];
  const float* b2  = (const float*)d_in[8];
  const float* W2r = (const float*)d_in[9];
  const float* g2  = (const float*)d_in[10];
  const float* be2 = (const float*)d_in[11];
  float* out = (float*)d_out;

  int n = in_sizes[0] / 128;
  int E = in_sizes[1] / 2;
  int nbk = (n + BSPAN - 1) / BSPAN;   // 196 for n=100000 (fits 256)
  int nce = (int)(((long long)E + CHUNK - 1) / CHUNK);
  long long n8 = (long long)n * 16;    // 8-elem chunks in x
  int ncast = (int)((n8 + 255) / 256);

  // workspace carve-up (aligned to 256B)
  char* ws = (char*)d_ws;
  size_t o = 0;
  auto carve = [&](size_t bytes) {
    char* p = ws + o;
    o += (bytes + 255) & ~(size_t)255;
    return p;
  };
  int*      bcnt   = (int*)carve(256 * 4);
  int*      bbase  = (int*)carve(256 * 4);
  int*      bcur   = (int*)carve(256 * 4);
  unsigned* epk    = (unsigned*)carve((size_t)E * 4);
  int*      ssrc   = (int*)carve((size_t)E * 4);
  int*      rowptr = (int*)carve((size_t)(n + 1) * 4);
  short*    wp1    = (short*)carve((size_t)64 * 64 * 8 * 2);  // 64 KB
  short*    wp2    = (short*)carve((size_t)32 * 64 * 8 * 2);  // 32 KB
  unsigned short* xbf   = (unsigned short*)carve((size_t)n * 128 * 2);
  unsigned short* aggbf = (unsigned short*)carve((size_t)n * 128 * 2);
  unsigned short* h1bf  = (unsigned short*)carve((size_t)n * 128 * 2);
  unsigned short* ybf   = (unsigned short*)carve((size_t)n * 64 * 2);

  hipMemsetAsync(bcnt, 0, 256 * 4, stream);

  // merged prep: cast + bucket histogram + weight packs (independent work)
  k_prep<<<ncast + nce + 24, 256, 0, stream>>>(
      x, xbf, n8, ei, bcnt, E, n, ncast, nce,
      W1l, W1r, wp1, W2l, W2r, wp2);
  k_bscan<<<1, 256, 0, stream>>>(bcnt, bbase, bcur, nbk);
  k_scatter<<<nce, 256, 0, stream>>>(ei, bcur, epk, E, n);
  k_build<<<nbk, 256, 0, stream>>>(epk, bbase, bcnt, rowptr, ssrc, n, nbk);

  {
    long long T = (long long)n * 64;
    k_agg1<<<(int)((T + 255) / 256), 256, 0, stream>>>(
        rowptr, ssrc, (const unsigned*)xbf, (unsigned*)aggbf, n);
  }
  k_lin1<<<(n + 63) / 64, 256, 0, stream>>>(xbf, aggbf, wp1, b1, g1, be1, h1bf, n);
  k_lin2<<<(n + 63) / 64, 256, 0, stream>>>(h1bf, wp2, b2, ybf, out, n);
  {
    long long T = (long long)n * 64;
    k_agg2<<<(int)((T + 255) / 256), 256, 0, stream>>>(
        rowptr, ssrc, (const unsigned*)ybf, g2, be2, out, n);
  }
}